// Round 2
// baseline (170.507 us; speedup 1.0000x reference)
//
#include <hip/hip_runtime.h>
#include <math.h>

#define B_ 4
#define N_ 64
#define L_ 128
#define H_ 8
#define E_ 32

// qm[b][h][e][t] = mean over n of queries[b,n,t,h,e]   (fp64 accumulate)
__global__ __launch_bounds__(256) void k_qmean(const float* __restrict__ q,
                                               float* __restrict__ qm) {
    int blk = blockIdx.x;               // b*128 + t
    int b = blk >> 7, t = blk & 127;
    int c = threadIdx.x;                // h*32 + e
    const float* p = q + (((size_t)(b * N_)) * L_ + t) * 256 + c;
    double s = 0.0;
    for (int n = 0; n < N_; ++n) s += (double)p[(size_t)n * L_ * 256];
    qm[((size_t)b * 256 + c) * L_ + t] = (float)(s * (1.0 / 64.0));
}

// wT[dt][lp*32+e] = w_cf[(e*128+lp)*3 + dt],  bT[lp*32+e] = b_cf[e*128+lp]
__global__ void k_prepwb(const float* __restrict__ w, const float* __restrict__ bias,
                         float* __restrict__ wT, float* __restrict__ bT) {
    int k = blockIdx.x * 256 + threadIdx.x;  // 4096 = lp*32+e
    int e = k & 31, lp = k >> 5;
    int c = e * L_ + lp;
    wT[k]          = w[c * 3 + 0];
    wT[4096 + k]   = w[c * 3 + 1];
    wT[8192 + k]   = w[c * 3 + 2];
    bT[k]          = bias[c];
}

// part[sc][b][n][h][tau] = sum_{s in 4-chunk sc, e} keys[b,n,s,h,e]*qm[b,h,e,(s+tau)%128]
// grid: ((b*8+h)*32 + sc) = 1024 blocks, 256 threads, thread tile 4n x 8tau, fp32 acc
// LDS: qs_t[t][e] (swizzled), as[ss][n][e] (swizzled) -> all reads are b128 conflict-free
__global__ __launch_bounds__(256) void k_corr(const float* __restrict__ keys,
                                              const float* __restrict__ qm,
                                              float* __restrict__ part) {
    int blk = blockIdx.x;
    int sc = blk & 31; int bh = blk >> 5; int h = bh & 7; int b = bh >> 3;
    __shared__ float qs_t[L_][E_];      // [t][e swizzled by t&7]   16KB
    __shared__ float as[2][N_][E_];     // [ss][n][e swizzled by (n>>2)&7] 16KB
    int tid = threadIdx.x;

    // stage qm rotated-source: qs_t[t][swz(e,t)] = qm[b,h,e,t]
    for (int k = tid; k < E_ * L_; k += 256) {
        int e = k >> 7, t = k & 127;
        int col = ((((e >> 2) ^ (t & 7)) << 2) | (e & 3));
        qs_t[t][col] = qm[((size_t)b * 256 + h * E_ + e) * L_ + t];
    }
    int tx = tid & 15, ty = tid >> 4;   // n = ty*4+i ; tau = tx + 16*j
    float acc[4][8];
    #pragma unroll
    for (int i = 0; i < 4; ++i)
        #pragma unroll
        for (int j = 0; j < 8; ++j) acc[i][j] = 0.f;

    for (int half = 0; half < 2; ++half) {
        __syncthreads();
        // load 2 s-planes of keys: as[ss][n][swz(e,n)] = keys[b,n,s,h,e]
        for (int k = tid; k < 2 * E_ * N_; k += 256) {
            int e = k & 31; int n = (k >> 5) & 63; int ss = k >> 11;
            int s = sc * 4 + half * 2 + ss;
            int col = ((((e >> 2) ^ ((n >> 2) & 7)) << 2) | (e & 3));
            as[ss][n][col] = keys[(((size_t)(b * N_ + n)) * L_ + s) * 256 + h * E_ + e];
        }
        __syncthreads();
        #pragma unroll
        for (int ss = 0; ss < 2; ++ss) {
            int sb = sc * 4 + half * 2 + ss;
            int t0 = sb + tx;                 // tau-base (mod later)
            int c4q = (t0 & 7);               // t&7 is j-invariant (j steps by 16)
            #pragma unroll
            for (int ee = 0; ee < 8; ++ee) {
                float4 a[4];
                #pragma unroll
                for (int i = 0; i < 4; ++i)
                    a[i] = *(const float4*)&as[ss][ty * 4 + i][(ee ^ (ty & 7)) << 2];
                int cq = (ee ^ c4q) << 2;
                #pragma unroll
                for (int j = 0; j < 8; ++j) {
                    int t = (t0 + 16 * j) & 127;
                    float4 bq = *(const float4*)&qs_t[t][cq];
                    #pragma unroll
                    for (int i = 0; i < 4; ++i) {
                        acc[i][j] = fmaf(a[i].x, bq.x, acc[i][j]);
                        acc[i][j] = fmaf(a[i].y, bq.y, acc[i][j]);
                        acc[i][j] = fmaf(a[i].z, bq.z, acc[i][j]);
                        acc[i][j] = fmaf(a[i].w, bq.w, acc[i][j]);
                    }
                }
            }
        }
    }
    #pragma unroll
    for (int i = 0; i < 4; ++i) {
        int n = ty * 4 + i;
        size_t o = ((((size_t)sc * B_ + b) * N_ + n) * H_ + h) * L_;
        #pragma unroll
        for (int j = 0; j < 8; ++j) part[o + tx + 16 * j] = acc[i][j];
    }
}

// top-2 over tau per (b,n,h) + near-tie flag (v2 - v3 < margin)
__global__ __launch_bounds__(64) void k_topk(const float* __restrict__ part,
                                             int* __restrict__ didx,
                                             float* __restrict__ sig,
                                             int* __restrict__ flags) {
    int blk = blockIdx.x;               // (b*64+n)*8+h
    int lane = threadIdx.x;
    size_t rb = (size_t)blk * L_;
    const size_t stride = (size_t)B_ * N_ * H_ * L_;
    double s0 = 0.0, s1 = 0.0;
    for (int sc = 0; sc < 32; ++sc) {
        s0 += (double)part[sc * stride + rb + lane];
        s1 += (double)part[sc * stride + rb + lane + 64];
    }
    float v0 = (float)(s0 * (1.0 / 32.0));
    float v1 = (float)(s1 * (1.0 / 32.0));

    // pass 1: global max (tie -> lower index)
    float bv = v0; int bi = lane;
    if (v1 > v0) { bv = v1; bi = lane + 64; }
    #pragma unroll
    for (int m = 32; m; m >>= 1) {
        float ov = __shfl_xor(bv, m, 64);
        int   oi = __shfl_xor(bi, m, 64);
        if (ov > bv || (ov == bv && oi < bi)) { bv = ov; bi = oi; }
    }
    int i1 = bi; float w1v = bv;

    // pass 2
    float c0 = (lane == i1) ? -INFINITY : v0;
    float c1 = (lane + 64 == i1) ? -INFINITY : v1;
    float bv2 = c0; int bi2 = lane;
    if (c1 > c0) { bv2 = c1; bi2 = lane + 64; }
    #pragma unroll
    for (int m = 32; m; m >>= 1) {
        float ov = __shfl_xor(bv2, m, 64);
        int   oi = __shfl_xor(bi2, m, 64);
        if (ov > bv2 || (ov == bv2 && oi < bi2)) { bv2 = ov; bi2 = oi; }
    }
    int i2 = bi2; float w2v = bv2;

    // pass 3: third-best value only (for the near-tie flag)
    float d0 = (lane == i1 || lane == i2) ? -INFINITY : v0;
    float d1 = (lane + 64 == i1 || lane + 64 == i2) ? -INFINITY : v1;
    float bv3 = fmaxf(d0, d1);
    #pragma unroll
    for (int m = 32; m; m >>= 1) bv3 = fmaxf(bv3, __shfl_xor(bv3, m, 64));

    if (lane == 0) {
        didx[blk * 2 + 0] = i1;
        didx[blk * 2 + 1] = i2;
        sig[blk * 2 + 0] = 1.f / (1.f + expf(-w1v));
        sig[blk * 2 + 1] = 1.f / (1.f + expf(-w2v));
        flags[blk] = (w2v - bv3 < 1e-3f) ? 1 : 0;
    }
}

// exact fp64 recompute of flagged rows; overwrites didx/sig (jax tie semantics)
__global__ __launch_bounds__(256) void k_fixup(const float* __restrict__ keys,
                                               const float* __restrict__ qm,
                                               const int* __restrict__ flags,
                                               int* __restrict__ didx,
                                               float* __restrict__ sig) {
    int row = blockIdx.x;               // (b*64+n)*8+h
    if (!flags[row]) return;
    int h = row & 7; int r = row >> 3; int n = r & 63; int b = r >> 6;
    __shared__ float ks[E_][L_];
    __shared__ float qsl[E_][L_];
    __shared__ double vv[2][L_];
    int tid = threadIdx.x;
    for (int k = tid; k < E_ * L_; k += 256) {
        int e = k & 31; int s = k >> 5;
        ks[e][s]  = keys[(((size_t)(b * N_ + n)) * L_ + s) * 256 + h * E_ + e];
        qsl[e][s] = qm[((size_t)b * 256 + h * E_ + e) * L_ + s];
    }
    __syncthreads();
    int tau = tid & 127, hf = tid >> 7;
    double acc = 0.0;
    for (int e = 0; e < E_; ++e) {
        #pragma unroll 8
        for (int s = hf * 64; s < hf * 64 + 64; ++s)
            acc = fma((double)ks[e][s], (double)qsl[e][(s + tau) & 127], acc);
    }
    vv[hf][tau] = acc;
    __syncthreads();
    if (tid == 0) {
        double bv = -1e300, bv2 = -1e300; int bi = 0, bi2 = 0;
        for (int t = 0; t < L_; ++t) {
            double v = (vv[0][t] + vv[1][t]) * (1.0 / 32.0);
            if (v > bv) { bv2 = bv; bi2 = bi; bv = v; bi = t; }
            else if (v > bv2) { bv2 = v; bi2 = t; }
        }
        didx[row * 2 + 0] = bi;
        didx[row * 2 + 1] = bi2;
        sig[row * 2 + 0] = 1.f / (1.f + expf(-(float)bv));
        sig[row * 2 + 1] = 1.f / (1.f + expf(-(float)bv2));
    }
}

// stable argsort by (delay asc, n asc) over N=64; emit sorted-order predecessors
__global__ __launch_bounds__(128) void k_sort(const int* __restrict__ didx,
                                              int* __restrict__ pred) {
    int bh = blockIdx.x;                // b*8+h
    int b = bh >> 3, h = bh & 7;
    int tid = threadIdx.x; int i = tid >> 6; int n = tid & 63;
    __shared__ int ds[2][64];
    __shared__ int pm[2][64];
    int d = 128 - didx[((b * 64 + n) * 8 + h) * 2 + i];
    ds[i][n] = d;
    __syncthreads();
    int rank = 0;
    for (int m = 0; m < 64; ++m) {
        int dm = ds[i][m];
        rank += (dm < d || (dm == d && m < n)) ? 1 : 0;
    }
    pm[i][rank] = n;
    __syncthreads();
    int p1v = (rank >= 1) ? pm[i][rank - 1] : -1;
    int p2v = (rank >= 2) ? pm[i][rank - 2] : -1;
    int o = ((bh * 2 + i) * 64 + n) * 2;
    pred[o] = p1v; pred[o + 1] = p2v;
}

// final gather: V[b,n,t,h,e] = 0.5 * sum_i [ b[c] + w2[c]*sig_n*v(n,t)
//   + w1[c]*sig_p1*v(p1,(t+di_n-di_p1)%128) + w0[c]*sig_p2*v(p2,(t+di_n-di_p2)%128) ]
__global__ __launch_bounds__(256) void k_out(const float* __restrict__ values,
                                             const float* __restrict__ wT,
                                             const float* __restrict__ bT,
                                             const int* __restrict__ didx,
                                             const float* __restrict__ sig,
                                             const int* __restrict__ pred,
                                             float* __restrict__ out) {
    int blk = blockIdx.x;               // (b*64+n)*8+h
    int h = blk & 7; int r = blk >> 3; int n = r & 63; int b = r >> 6;
    int tid = threadIdx.x; int e = tid & 31; int tr = tid >> 5;

    int di[2], dp1[2], dp2[2], p1[2], p2[2];
    float si[2], s1[2], s2[2];
    #pragma unroll
    for (int i = 0; i < 2; ++i) {
        di[i] = didx[blk * 2 + i];
        si[i] = sig[blk * 2 + i];
        int po = (((b * 8 + h) * 2 + i) * 64 + n) * 2;
        p1[i] = pred[po]; p2[i] = pred[po + 1];
        if (p1[i] >= 0) {
            int qidx = ((b * 64 + p1[i]) * 8 + h) * 2 + i;
            dp1[i] = didx[qidx]; s1[i] = sig[qidx];
        } else { dp1[i] = 0; s1[i] = 0.f; }
        if (p2[i] >= 0) {
            int qidx = ((b * 64 + p2[i]) * 8 + h) * 2 + i;
            dp2[i] = didx[qidx]; s2[i] = sig[qidx];
        } else { dp2[i] = 0; s2[i] = 0.f; }
    }
    const size_t vbase = ((size_t)b * N_) * L_ * 256 + h * E_ + e;
    const size_t obase = (((size_t)(b * N_ + n)) * L_) * 256 + h * E_ + e;

    for (int it = 0; it < 16; ++it) {
        int t = tr + 8 * it;
        float vself = values[vbase + ((size_t)n * L_ + t) * 256];
        float acc = 0.f;
        #pragma unroll
        for (int i = 0; i < 2; ++i) {
            int lp = (t + di[i]) & 127;
            int wo = lp * 32 + e;
            acc += bT[wo] + wT[8192 + wo] * si[i] * vself;
            if (p1[i] >= 0) {
                int t1 = (t + di[i] - dp1[i]) & 127;
                acc += wT[4096 + wo] * s1[i] * values[vbase + ((size_t)p1[i] * L_ + t1) * 256];
            }
            if (p2[i] >= 0) {
                int t2 = (t + di[i] - dp2[i]) & 127;
                acc += wT[wo] * s2[i] * values[vbase + ((size_t)p2[i] * L_ + t2) * 256];
            }
        }
        out[obase + (size_t)t * 256] = acc * 0.5f;
    }
}

extern "C" void kernel_launch(void* const* d_in, const int* in_sizes, int n_in,
                              void* d_out, int out_size, void* d_ws, size_t ws_size,
                              hipStream_t stream) {
    const float* queries = (const float*)d_in[0];
    const float* keys    = (const float*)d_in[1];
    const float* values  = (const float*)d_in[2];
    // d_in[3] = attn_mask (unused)
    const float* w_cf = (const float*)d_in[4];
    const float* b_cf = (const float*)d_in[5];
    float* out = (float*)d_out;

    // workspace layout (~660 KB)
    float* ws    = (float*)d_ws;
    float* qm    = ws;                    // 131072 f
    float* wT    = qm + 131072;           // 12288 f
    float* bT    = wT + 12288;            // 4096 f
    float* sigp  = bT + 4096;             // 4096 f
    int*   didxp = (int*)(sigp + 4096);   // 4096 i
    int*   predp = didxp + 4096;          // 8192 i
    int*   flags = predp + 8192;          // 2048 i

    // 32 MB of corr partials live in d_out (written by k_corr, read by k_topk,
    // then d_out is fully overwritten by k_out). 32*262144 == out_size exactly.
    float* part = (float*)d_out;

    k_qmean <<<512,  256, 0, stream>>>(queries, qm);
    k_prepwb<<<16,   256, 0, stream>>>(w_cf, b_cf, wT, bT);
    k_corr  <<<1024, 256, 0, stream>>>(keys, qm, part);
    k_topk  <<<2048, 64,  0, stream>>>(part, didxp, sigp, flags);
    k_fixup <<<2048, 256, 0, stream>>>(keys, qm, flags, didxp, sigp);
    k_sort  <<<32,   128, 0, stream>>>(didxp, predp);
    k_out   <<<2048, 256, 0, stream>>>(values, wT, bT, didxp, sigp, predp, out);
}

// Round 3
// 130.814 us; speedup vs baseline: 1.3034x; 1.3034x over previous
//
#include <hip/hip_runtime.h>
#include <math.h>

#define B_ 4
#define N_ 64
#define L_ 128
#define H_ 8
#define E_ 32

// qm[b][h][e][t] = mean over n of queries[b,n,t,h,e]   (fp64 accumulate)
__global__ __launch_bounds__(256) void k_qmean(const float* __restrict__ q,
                                               float* __restrict__ qm) {
    int blk = blockIdx.x;               // b*128 + t
    int b = blk >> 7, t = blk & 127;
    int c = threadIdx.x;                // h*32 + e
    const float* p = q + (((size_t)(b * N_)) * L_ + t) * 256 + c;
    double s = 0.0;
    for (int n = 0; n < N_; ++n) s += (double)p[(size_t)n * L_ * 256];
    qm[((size_t)b * 256 + c) * L_ + t] = (float)(s * (1.0 / 64.0));
}

// wT[dt][lp*32+e] = w_cf[(e*128+lp)*3 + dt],  bT[lp*32+e] = b_cf[e*128+lp]
__global__ void k_prepwb(const float* __restrict__ w, const float* __restrict__ bias,
                         float* __restrict__ wT, float* __restrict__ bT) {
    int k = blockIdx.x * 256 + threadIdx.x;  // 4096 = lp*32+e
    int e = k & 31, lp = k >> 5;
    int c = e * L_ + lp;
    wT[k]          = w[c * 3 + 0];
    wT[4096 + k]   = w[c * 3 + 1];
    wT[8192 + k]   = w[c * 3 + 2];
    bT[k]          = bias[c];
}

// part[sc][b][n][h][tau] = sum_{s in 4-chunk sc, e} keys[b,n,s,h,e]*qm[b,h,e,(s+tau)%128]
// grid: ((b*8+h)*32 + sc) = 1024 blocks, 256 threads, thread tile 4n x 8tau, fp32 acc
__global__ __launch_bounds__(256) void k_corr(const float* __restrict__ keys,
                                              const float* __restrict__ qm,
                                              float* __restrict__ part) {
    int blk = blockIdx.x;
    int sc = blk & 31; int bh = blk >> 5; int h = bh & 7; int b = bh >> 3;
    __shared__ float qs_t[L_][E_];      // [t][e swizzled by t&7]   16KB
    __shared__ float as[2][N_][E_];     // [ss][n][e swizzled by (n>>2)&7] 16KB
    int tid = threadIdx.x;

    for (int k = tid; k < E_ * L_; k += 256) {
        int e = k >> 7, t = k & 127;
        int col = ((((e >> 2) ^ (t & 7)) << 2) | (e & 3));
        qs_t[t][col] = qm[((size_t)b * 256 + h * E_ + e) * L_ + t];
    }
    int tx = tid & 15, ty = tid >> 4;   // n = ty*4+i ; tau = tx + 16*j
    float acc[4][8];
    #pragma unroll
    for (int i = 0; i < 4; ++i)
        #pragma unroll
        for (int j = 0; j < 8; ++j) acc[i][j] = 0.f;

    for (int half = 0; half < 2; ++half) {
        __syncthreads();
        for (int k = tid; k < 2 * E_ * N_; k += 256) {
            int e = k & 31; int n = (k >> 5) & 63; int ss = k >> 11;
            int s = sc * 4 + half * 2 + ss;
            int col = ((((e >> 2) ^ ((n >> 2) & 7)) << 2) | (e & 3));
            as[ss][n][col] = keys[(((size_t)(b * N_ + n)) * L_ + s) * 256 + h * E_ + e];
        }
        __syncthreads();
        #pragma unroll
        for (int ss = 0; ss < 2; ++ss) {
            int sb = sc * 4 + half * 2 + ss;
            int t0 = sb + tx;
            int c4q = (t0 & 7);
            #pragma unroll
            for (int ee = 0; ee < 8; ++ee) {
                float4 a[4];
                #pragma unroll
                for (int i = 0; i < 4; ++i)
                    a[i] = *(const float4*)&as[ss][ty * 4 + i][(ee ^ (ty & 7)) << 2];
                int cq = (ee ^ c4q) << 2;
                #pragma unroll
                for (int j = 0; j < 8; ++j) {
                    int t = (t0 + 16 * j) & 127;
                    float4 bq = *(const float4*)&qs_t[t][cq];
                    #pragma unroll
                    for (int i = 0; i < 4; ++i) {
                        acc[i][j] = fmaf(a[i].x, bq.x, acc[i][j]);
                        acc[i][j] = fmaf(a[i].y, bq.y, acc[i][j]);
                        acc[i][j] = fmaf(a[i].z, bq.z, acc[i][j]);
                        acc[i][j] = fmaf(a[i].w, bq.w, acc[i][j]);
                    }
                }
            }
        }
    }
    #pragma unroll
    for (int i = 0; i < 4; ++i) {
        int n = ty * 4 + i;
        size_t o = ((((size_t)sc * B_ + b) * N_ + n) * H_ + h) * L_;
        #pragma unroll
        for (int j = 0; j < 8; ++j) part[o + tx + 16 * j] = acc[i][j];
    }
}

// top-2 over tau per (b,n,h) + near-tie flag (v2 - v3 < margin)
__global__ __launch_bounds__(64) void k_topk(const float* __restrict__ part,
                                             int* __restrict__ didx,
                                             float* __restrict__ sig,
                                             int* __restrict__ flags) {
    int blk = blockIdx.x;               // (b*64+n)*8+h
    int lane = threadIdx.x;
    size_t rb = (size_t)blk * L_;
    const size_t stride = (size_t)B_ * N_ * H_ * L_;
    double s0 = 0.0, s1 = 0.0;
    for (int sc = 0; sc < 32; ++sc) {
        s0 += (double)part[sc * stride + rb + lane];
        s1 += (double)part[sc * stride + rb + lane + 64];
    }
    float v0 = (float)(s0 * (1.0 / 32.0));
    float v1 = (float)(s1 * (1.0 / 32.0));

    float bv = v0; int bi = lane;
    if (v1 > v0) { bv = v1; bi = lane + 64; }
    #pragma unroll
    for (int m = 32; m; m >>= 1) {
        float ov = __shfl_xor(bv, m, 64);
        int   oi = __shfl_xor(bi, m, 64);
        if (ov > bv || (ov == bv && oi < bi)) { bv = ov; bi = oi; }
    }
    int i1 = bi; float w1v = bv;

    float c0 = (lane == i1) ? -INFINITY : v0;
    float c1 = (lane + 64 == i1) ? -INFINITY : v1;
    float bv2 = c0; int bi2 = lane;
    if (c1 > c0) { bv2 = c1; bi2 = lane + 64; }
    #pragma unroll
    for (int m = 32; m; m >>= 1) {
        float ov = __shfl_xor(bv2, m, 64);
        int   oi = __shfl_xor(bi2, m, 64);
        if (ov > bv2 || (ov == bv2 && oi < bi2)) { bv2 = ov; bi2 = oi; }
    }
    int i2 = bi2; float w2v = bv2;

    float d0 = (lane == i1 || lane == i2) ? -INFINITY : v0;
    float d1 = (lane + 64 == i1 || lane + 64 == i2) ? -INFINITY : v1;
    float bv3 = fmaxf(d0, d1);
    #pragma unroll
    for (int m = 32; m; m >>= 1) bv3 = fmaxf(bv3, __shfl_xor(bv3, m, 64));

    if (lane == 0) {
        didx[blk * 2 + 0] = i1;
        didx[blk * 2 + 1] = i2;
        sig[blk * 2 + 0] = 1.f / (1.f + expf(-w1v));
        sig[blk * 2 + 1] = 1.f / (1.f + expf(-w2v));
        flags[blk] = (w2v - bv3 < 1e-3f) ? 1 : 0;
    }
}

// exact fp64 recompute of flagged rows; overwrites didx/sig (jax tie semantics).
// 512 thr = 128 tau x 4 e-groups; [s][e] LDS layout, swizzled q tile, 8 indep fp64 chains.
__global__ __launch_bounds__(512) void k_fixup(const float* __restrict__ keys,
                                               const float* __restrict__ qm,
                                               const int* __restrict__ flags,
                                               int* __restrict__ didx,
                                               float* __restrict__ sig) {
    int row = blockIdx.x;               // (b*64+n)*8+h
    if (!flags[row]) return;
    int h = row & 7; int r = row >> 3; int n = r & 63; int b = r >> 6;
    __shared__ float ks_t[L_][E_];      // [s][e] plain (reads are broadcast)
    __shared__ float qs_t[L_][E_];      // [t][e] swizzled by t&7
    __shared__ double vv[4][L_];
    int tid = threadIdx.x;
    for (int k = tid; k < E_ * L_; k += 512) {
        int e = k & 31; int s = k >> 5;
        ks_t[s][e] = keys[(((size_t)(b * N_ + n)) * L_ + s) * 256 + h * E_ + e];
        int col = ((((e >> 2) ^ (s & 7)) << 2) | (e & 3));
        qs_t[s][col] = qm[((size_t)b * 256 + h * E_ + e) * L_ + s];
    }
    __syncthreads();
    int tau = tid & 127, g = tid >> 7;  // e-group base = g*8
    double acc[8];
    #pragma unroll
    for (int i = 0; i < 8; ++i) acc[i] = 0.0;
    for (int s = 0; s < L_; ++s) {
        int t = (s + tau) & 127;
        float4 k0 = *(const float4*)&ks_t[s][g * 8];
        float4 k1 = *(const float4*)&ks_t[s][g * 8 + 4];
        float4 q0 = *(const float4*)&qs_t[t][((2 * g) ^ (t & 7)) << 2];
        float4 q1 = *(const float4*)&qs_t[t][((2 * g + 1) ^ (t & 7)) << 2];
        acc[0] = fma((double)k0.x, (double)q0.x, acc[0]);
        acc[1] = fma((double)k0.y, (double)q0.y, acc[1]);
        acc[2] = fma((double)k0.z, (double)q0.z, acc[2]);
        acc[3] = fma((double)k0.w, (double)q0.w, acc[3]);
        acc[4] = fma((double)k1.x, (double)q1.x, acc[4]);
        acc[5] = fma((double)k1.y, (double)q1.y, acc[5]);
        acc[6] = fma((double)k1.z, (double)q1.z, acc[6]);
        acc[7] = fma((double)k1.w, (double)q1.w, acc[7]);
    }
    vv[g][tau] = ((acc[0] + acc[1]) + (acc[2] + acc[3])) +
                 ((acc[4] + acc[5]) + (acc[6] + acc[7]));
    __syncthreads();
    if (tid < 64) {
        int lane = tid;
        float v0 = (float)((vv[0][lane] + vv[1][lane] + vv[2][lane] + vv[3][lane]) * (1.0 / 32.0));
        float v1 = (float)((vv[0][lane + 64] + vv[1][lane + 64] + vv[2][lane + 64] + vv[3][lane + 64]) * (1.0 / 32.0));

        float bv = v0; int bi = lane;
        if (v1 > v0) { bv = v1; bi = lane + 64; }
        #pragma unroll
        for (int m = 32; m; m >>= 1) {
            float ov = __shfl_xor(bv, m, 64);
            int   oi = __shfl_xor(bi, m, 64);
            if (ov > bv || (ov == bv && oi < bi)) { bv = ov; bi = oi; }
        }
        int i1 = bi; float w1v = bv;

        float c0 = (lane == i1) ? -INFINITY : v0;
        float c1 = (lane + 64 == i1) ? -INFINITY : v1;
        float bv2 = c0; int bi2 = lane;
        if (c1 > c0) { bv2 = c1; bi2 = lane + 64; }
        #pragma unroll
        for (int m = 32; m; m >>= 1) {
            float ov = __shfl_xor(bv2, m, 64);
            int   oi = __shfl_xor(bi2, m, 64);
            if (ov > bv2 || (ov == bv2 && oi < bi2)) { bv2 = ov; bi2 = oi; }
        }
        if (lane == 0) {
            didx[row * 2 + 0] = i1;
            didx[row * 2 + 1] = bi2;
            sig[row * 2 + 0] = 1.f / (1.f + expf(-w1v));
            sig[row * 2 + 1] = 1.f / (1.f + expf(-bv2));
        }
    }
}

// stable argsort by (delay asc, n asc) over N=64; emit sorted-order predecessors
__global__ __launch_bounds__(128) void k_sort(const int* __restrict__ didx,
                                              int* __restrict__ pred) {
    int bh = blockIdx.x;                // b*8+h
    int b = bh >> 3, h = bh & 7;
    int tid = threadIdx.x; int i = tid >> 6; int n = tid & 63;
    __shared__ int ds[2][64];
    __shared__ int pm[2][64];
    int d = 128 - didx[((b * 64 + n) * 8 + h) * 2 + i];
    ds[i][n] = d;
    __syncthreads();
    int rank = 0;
    for (int m = 0; m < 64; ++m) {
        int dm = ds[i][m];
        rank += (dm < d || (dm == d && m < n)) ? 1 : 0;
    }
    pm[i][rank] = n;
    __syncthreads();
    int p1v = (rank >= 1) ? pm[i][rank - 1] : -1;
    int p2v = (rank >= 2) ? pm[i][rank - 2] : -1;
    int o = ((bh * 2 + i) * 64 + n) * 2;
    pred[o] = p1v; pred[o + 1] = p2v;
}

// final gather: V[b,n,t,h,e] = 0.5 * sum_i [ b[c] + w2[c]*sig_n*v(n,t)
//   + w1[c]*sig_p1*v(p1,...) + w0[c]*sig_p2*v(p2,...) ]
__global__ __launch_bounds__(256) void k_out(const float* __restrict__ values,
                                             const float* __restrict__ wT,
                                             const float* __restrict__ bT,
                                             const int* __restrict__ didx,
                                             const float* __restrict__ sig,
                                             const int* __restrict__ pred,
                                             float* __restrict__ out) {
    int blk = blockIdx.x;               // (b*64+n)*8+h
    int h = blk & 7; int r = blk >> 3; int n = r & 63; int b = r >> 6;
    int tid = threadIdx.x; int e = tid & 31; int tr = tid >> 5;

    int di[2], dp1[2], dp2[2], p1[2], p2[2];
    float si[2], s1[2], s2[2];
    #pragma unroll
    for (int i = 0; i < 2; ++i) {
        di[i] = didx[blk * 2 + i];
        si[i] = sig[blk * 2 + i];
        int po = (((b * 8 + h) * 2 + i) * 64 + n) * 2;
        p1[i] = pred[po]; p2[i] = pred[po + 1];
        if (p1[i] >= 0) {
            int qidx = ((b * 64 + p1[i]) * 8 + h) * 2 + i;
            dp1[i] = didx[qidx]; s1[i] = sig[qidx];
        } else { dp1[i] = 0; s1[i] = 0.f; }
        if (p2[i] >= 0) {
            int qidx = ((b * 64 + p2[i]) * 8 + h) * 2 + i;
            dp2[i] = didx[qidx]; s2[i] = sig[qidx];
        } else { dp2[i] = 0; s2[i] = 0.f; }
    }
    const size_t vbase = ((size_t)b * N_) * L_ * 256 + h * E_ + e;
    const size_t obase = (((size_t)(b * N_ + n)) * L_) * 256 + h * E_ + e;

    for (int it = 0; it < 16; ++it) {
        int t = tr + 8 * it;
        float vself = values[vbase + ((size_t)n * L_ + t) * 256];
        float acc = 0.f;
        #pragma unroll
        for (int i = 0; i < 2; ++i) {
            int lp = (t + di[i]) & 127;
            int wo = lp * 32 + e;
            acc += bT[wo] + wT[8192 + wo] * si[i] * vself;
            if (p1[i] >= 0) {
                int t1 = (t + di[i] - dp1[i]) & 127;
                acc += wT[4096 + wo] * s1[i] * values[vbase + ((size_t)p1[i] * L_ + t1) * 256];
            }
            if (p2[i] >= 0) {
                int t2 = (t + di[i] - dp2[i]) & 127;
                acc += wT[wo] * s2[i] * values[vbase + ((size_t)p2[i] * L_ + t2) * 256];
            }
        }
        out[obase + (size_t)t * 256] = acc * 0.5f;
    }
}

extern "C" void kernel_launch(void* const* d_in, const int* in_sizes, int n_in,
                              void* d_out, int out_size, void* d_ws, size_t ws_size,
                              hipStream_t stream) {
    const float* queries = (const float*)d_in[0];
    const float* keys    = (const float*)d_in[1];
    const float* values  = (const float*)d_in[2];
    const float* w_cf = (const float*)d_in[4];
    const float* b_cf = (const float*)d_in[5];
    float* out = (float*)d_out;

    float* ws    = (float*)d_ws;
    float* qm    = ws;                    // 131072 f
    float* wT    = qm + 131072;           // 12288 f
    float* bT    = wT + 12288;            // 4096 f
    float* sigp  = bT + 4096;             // 4096 f
    int*   didxp = (int*)(sigp + 4096);   // 4096 i
    int*   predp = didxp + 4096;          // 8192 i
    int*   flags = predp + 8192;          // 2048 i

    // 32 MB of corr partials live in d_out (fully overwritten by k_out)
    float* part = (float*)d_out;

    k_qmean <<<512,  256, 0, stream>>>(queries, qm);
    k_prepwb<<<16,   256, 0, stream>>>(w_cf, b_cf, wT, bT);
    k_corr  <<<1024, 256, 0, stream>>>(keys, qm, part);
    k_topk  <<<2048, 64,  0, stream>>>(part, didxp, sigp, flags);
    k_fixup <<<2048, 512, 0, stream>>>(keys, qm, flags, didxp, sigp);
    k_sort  <<<32,   128, 0, stream>>>(didxp, predp);
    k_out   <<<2048, 256, 0, stream>>>(values, wT, bT, didxp, sigp, predp, out);
}

// Round 4
// 100.370 us; speedup vs baseline: 1.6988x; 1.3033x over previous
//
#include <hip/hip_runtime.h>
#include <math.h>

#define B_ 4
#define N_ 64
#define L_ 128
#define H_ 8
#define E_ 32
#define SC_ 8

typedef __attribute__((ext_vector_type(8))) short short8;
typedef __attribute__((ext_vector_type(4))) float f32x4;

__device__ __forceinline__ unsigned short f2bf(float x) {
    union { float f; unsigned u; } c; c.f = x;
    unsigned r = (c.u + 0x7fffu + ((c.u >> 16) & 1u)) >> 16;
    return (unsigned short)r;
}
__device__ __forceinline__ float bf2f(unsigned short h) {
    union { unsigned u; float f; } c; c.u = ((unsigned)h) << 16;
    return c.f;
}

// qm[b][h][e][t] = mean over n of queries[b,n,t,h,e]   (fp64 accumulate)
__global__ __launch_bounds__(256) void k_qmean(const float* __restrict__ q,
                                               float* __restrict__ qm) {
    int blk = blockIdx.x;               // b*128 + t
    int b = blk >> 7, t = blk & 127;
    int c = threadIdx.x;                // h*32 + e
    const float* p = q + (((size_t)(b * N_)) * L_ + t) * 256 + c;
    double s = 0.0;
    for (int n = 0; n < N_; ++n) s += (double)p[(size_t)n * L_ * 256];
    qm[((size_t)b * 256 + c) * L_ + t] = (float)(s * (1.0 / 64.0));
}

// wT[dt][lp*32+e] = w_cf[(e*128+lp)*3 + dt],  bT[lp*32+e] = b_cf[e*128+lp]
__global__ void k_prepwb(const float* __restrict__ w, const float* __restrict__ bias,
                         float* __restrict__ wT, float* __restrict__ bT) {
    int k = blockIdx.x * 256 + threadIdx.x;  // 4096 = lp*32+e
    int e = k & 31, lp = k >> 5;
    int c = e * L_ + lp;
    wT[k]          = w[c * 3 + 0];
    wT[4096 + k]   = w[c * 3 + 1];
    wT[8192 + k]   = w[c * 3 + 2];
    bT[k]          = bias[c];
}

// MFMA corr: part[sc][b][n][h][tau] = sum_{s in chunk, e} keys[b,n,s,h,e]*qm[b,h,e,(s+tau)%128]
// split-bf16 (hi+lo, 3 MFMAs: hh + hl + lh), mfma_f32_16x16x32_bf16, K=32 = one s-plane.
// 256 blocks = (b*8+h)*8+sc, 512 threads = 8 waves; wave owns 2Mx2N 16x16 tiles.
__global__ __launch_bounds__(512) void k_corr(const float* __restrict__ keys,
                                              const float* __restrict__ qm,
                                              float* __restrict__ part) {
    int blk = blockIdx.x;
    int sc = blk & 7; int bh = blk >> 3; int h = bh & 7; int b = bh >> 3;
    // padded stride 40 ushorts (=20 words) -> 8-phase-optimal b128 reads
    __shared__ unsigned short Ahi[4][64][40];   // 20 KB
    __shared__ unsigned short Alo[4][64][40];   // 20 KB
    __shared__ unsigned short Qhi[128][40];     // 10 KB
    __shared__ unsigned short Qlo[128][40];     // 10 KB
    int tid = threadIdx.x;
    int lane = tid & 63, w = tid >> 6;
    int mg = w & 1, ng = w >> 1;                // wave tile: M-tiles mg*2+{0,1}, N-tiles ng*2+{0,1}

    // ---- prologue: stage Q panel (hi/lo) as [t][e]
    {
        int e = tid >> 4; int tq = (tid & 15) * 4;
        const float* qp = qm + ((size_t)b * 256 + h * 32 + e) * 128;
        #pragma unroll
        for (int hf = 0; hf < 2; ++hf) {
            int t0 = tq + hf * 64;
            float4 v = *(const float4*)(qp + t0);
            float vv[4] = {v.x, v.y, v.z, v.w};
            #pragma unroll
            for (int j = 0; j < 4; ++j) {
                unsigned short hi = f2bf(vv[j]);
                Qhi[t0 + j][e] = hi;
                Qlo[t0 + j][e] = f2bf(vv[j] - bf2f(hi));
            }
        }
    }
    // ---- prologue: stage A planes 0,1
    int sn = tid >> 3; int se = (tid & 7) * 4;
    const float* kbase = keys + ((size_t)(b * N_ + sn) * L_) * 256 + h * 32 + se;
    #pragma unroll
    for (int p = 0; p < 2; ++p) {
        float4 v = *(const float4*)(kbase + (size_t)(sc * 16 + p) * 256);
        float vv[4] = {v.x, v.y, v.z, v.w};
        ushort4 h4, l4;
        unsigned short* hp = (unsigned short*)&h4;
        unsigned short* lp = (unsigned short*)&l4;
        #pragma unroll
        for (int j = 0; j < 4; ++j) {
            hp[j] = f2bf(vv[j]);
            lp[j] = f2bf(vv[j] - bf2f(hp[j]));
        }
        *(ushort4*)&Ahi[p][sn][se] = h4;
        *(ushort4*)&Alo[p][sn][se] = l4;
    }
    __syncthreads();

    f32x4 acc[2][2];
    #pragma unroll
    for (int i = 0; i < 2; ++i)
        #pragma unroll
        for (int j = 0; j < 2; ++j)
            acc[i][j] = (f32x4){0.f, 0.f, 0.f, 0.f};

    int eb = (lane >> 4) * 8;                   // e-block base within fragment
    int rA0 = (mg * 2) * 16 + (lane & 15);      // A rows for the wave's 2 M-tiles
    int rA1 = rA0 + 16;
    int tau0 = (ng * 2) * 16 + (lane & 15);     // taus for the wave's 2 N-tiles
    int tau1 = tau0 + 16;

    for (int it = 0; it < 8; ++it) {
        // (a) issue next plane-pair global loads (latency hides under MFMA)
        float4 stg0, stg1;
        if (it < 7) {
            stg0 = *(const float4*)(kbase + (size_t)(sc * 16 + 2 * it + 2) * 256);
            stg1 = *(const float4*)(kbase + (size_t)(sc * 16 + 2 * it + 3) * 256);
        }
        // (b) compute planes 2it, 2it+1
        #pragma unroll
        for (int sp = 0; sp < 2; ++sp) {
            int p = 2 * it + sp;
            int slot = p & 3;
            int s = sc * 16 + p;
            short8 ah0 = *(const short8*)&Ahi[slot][rA0][eb];
            short8 ah1 = *(const short8*)&Ahi[slot][rA1][eb];
            short8 al0 = *(const short8*)&Alo[slot][rA0][eb];
            short8 al1 = *(const short8*)&Alo[slot][rA1][eb];
            int t0 = (s + tau0) & 127;
            int t1 = (s + tau1) & 127;
            short8 bh0 = *(const short8*)&Qhi[t0][eb];
            short8 bh1 = *(const short8*)&Qhi[t1][eb];
            short8 bl0 = *(const short8*)&Qlo[t0][eb];
            short8 bl1 = *(const short8*)&Qlo[t1][eb];
            // hh (4 independent chains)
            acc[0][0] = __builtin_amdgcn_mfma_f32_16x16x32_bf16(ah0, bh0, acc[0][0], 0, 0, 0);
            acc[0][1] = __builtin_amdgcn_mfma_f32_16x16x32_bf16(ah0, bh1, acc[0][1], 0, 0, 0);
            acc[1][0] = __builtin_amdgcn_mfma_f32_16x16x32_bf16(ah1, bh0, acc[1][0], 0, 0, 0);
            acc[1][1] = __builtin_amdgcn_mfma_f32_16x16x32_bf16(ah1, bh1, acc[1][1], 0, 0, 0);
            // hl
            acc[0][0] = __builtin_amdgcn_mfma_f32_16x16x32_bf16(ah0, bl0, acc[0][0], 0, 0, 0);
            acc[0][1] = __builtin_amdgcn_mfma_f32_16x16x32_bf16(ah0, bl1, acc[0][1], 0, 0, 0);
            acc[1][0] = __builtin_amdgcn_mfma_f32_16x16x32_bf16(ah1, bl0, acc[1][0], 0, 0, 0);
            acc[1][1] = __builtin_amdgcn_mfma_f32_16x16x32_bf16(ah1, bl1, acc[1][1], 0, 0, 0);
            // lh
            acc[0][0] = __builtin_amdgcn_mfma_f32_16x16x32_bf16(al0, bh0, acc[0][0], 0, 0, 0);
            acc[0][1] = __builtin_amdgcn_mfma_f32_16x16x32_bf16(al0, bh1, acc[0][1], 0, 0, 0);
            acc[1][0] = __builtin_amdgcn_mfma_f32_16x16x32_bf16(al1, bh0, acc[1][0], 0, 0, 0);
            acc[1][1] = __builtin_amdgcn_mfma_f32_16x16x32_bf16(al1, bh1, acc[1][1], 0, 0, 0);
        }
        // (c) convert + LDS-write the prefetched planes into slots (2it+2)&3, (2it+3)&3
        if (it < 7) {
            #pragma unroll
            for (int sp = 0; sp < 2; ++sp) {
                int p = 2 * it + 2 + sp;
                int slot = p & 3;
                float4 v = sp ? stg1 : stg0;
                float vv[4] = {v.x, v.y, v.z, v.w};
                ushort4 h4, l4;
                unsigned short* hp = (unsigned short*)&h4;
                unsigned short* lp = (unsigned short*)&l4;
                #pragma unroll
                for (int j = 0; j < 4; ++j) {
                    hp[j] = f2bf(vv[j]);
                    lp[j] = f2bf(vv[j] - bf2f(hp[j]));
                }
                *(ushort4*)&Ahi[slot][sn][se] = h4;
                *(ushort4*)&Alo[slot][sn][se] = l4;
            }
        }
        // (d) one barrier per iter: slots written here are read next iter
        __syncthreads();
    }

    // write partials: C/D layout col=lane&15 (tau), row=(lane>>4)*4+r (n)
    #pragma unroll
    for (int i = 0; i < 2; ++i) {
        int mt = mg * 2 + i;
        #pragma unroll
        for (int j = 0; j < 2; ++j) {
            int nt = ng * 2 + j;
            int tau = nt * 16 + (lane & 15);
            #pragma unroll
            for (int r = 0; r < 4; ++r) {
                int n = mt * 16 + (lane >> 4) * 4 + r;
                part[((((size_t)sc * B_ + b) * N_ + n) * H_ + h) * L_ + tau] = acc[i][j][r];
            }
        }
    }
}

// top-2 over tau per (b,n,h) + near-tie flag (v2 - v3 < margin)
__global__ __launch_bounds__(64) void k_topk(const float* __restrict__ part,
                                             int* __restrict__ didx,
                                             float* __restrict__ sig,
                                             int* __restrict__ flags) {
    int blk = blockIdx.x;               // (b*64+n)*8+h
    int lane = threadIdx.x;
    size_t rb = (size_t)blk * L_;
    const size_t stride = (size_t)B_ * N_ * H_ * L_;
    double s0 = 0.0, s1 = 0.0;
    for (int sc = 0; sc < SC_; ++sc) {
        s0 += (double)part[sc * stride + rb + lane];
        s1 += (double)part[sc * stride + rb + lane + 64];
    }
    float v0 = (float)(s0 * (1.0 / 32.0));
    float v1 = (float)(s1 * (1.0 / 32.0));

    float bv = v0; int bi = lane;
    if (v1 > v0) { bv = v1; bi = lane + 64; }
    #pragma unroll
    for (int m = 32; m; m >>= 1) {
        float ov = __shfl_xor(bv, m, 64);
        int   oi = __shfl_xor(bi, m, 64);
        if (ov > bv || (ov == bv && oi < bi)) { bv = ov; bi = oi; }
    }
    int i1 = bi; float w1v = bv;

    float c0 = (lane == i1) ? -INFINITY : v0;
    float c1 = (lane + 64 == i1) ? -INFINITY : v1;
    float bv2 = c0; int bi2 = lane;
    if (c1 > c0) { bv2 = c1; bi2 = lane + 64; }
    #pragma unroll
    for (int m = 32; m; m >>= 1) {
        float ov = __shfl_xor(bv2, m, 64);
        int   oi = __shfl_xor(bi2, m, 64);
        if (ov > bv2 || (ov == bv2 && oi < bi2)) { bv2 = ov; bi2 = oi; }
    }
    int i2 = bi2; float w2v = bv2;

    float d0 = (lane == i1 || lane == i2) ? -INFINITY : v0;
    float d1 = (lane + 64 == i1 || lane + 64 == i2) ? -INFINITY : v1;
    float bv3 = fmaxf(d0, d1);
    #pragma unroll
    for (int m = 32; m; m >>= 1) bv3 = fmaxf(bv3, __shfl_xor(bv3, m, 64));

    if (lane == 0) {
        didx[blk * 2 + 0] = i1;
        didx[blk * 2 + 1] = i2;
        sig[blk * 2 + 0] = 1.f / (1.f + expf(-w1v));
        sig[blk * 2 + 1] = 1.f / (1.f + expf(-w2v));
        flags[blk] = (w2v - bv3 < 1e-3f) ? 1 : 0;
    }
}

// exact fp64 recompute of flagged rows; overwrites didx/sig (jax tie semantics).
__global__ __launch_bounds__(512) void k_fixup(const float* __restrict__ keys,
                                               const float* __restrict__ qm,
                                               const int* __restrict__ flags,
                                               int* __restrict__ didx,
                                               float* __restrict__ sig) {
    int row = blockIdx.x;               // (b*64+n)*8+h
    if (!flags[row]) return;
    int h = row & 7; int r = row >> 3; int n = r & 63; int b = r >> 6;
    __shared__ float ks_t[L_][E_];      // [s][e] plain (reads broadcast)
    __shared__ float qs_t[L_][E_];      // [t][e] swizzled by t&7
    __shared__ double vv[4][L_];
    int tid = threadIdx.x;
    for (int k = tid; k < E_ * L_; k += 512) {
        int e = k & 31; int s = k >> 5;
        ks_t[s][e] = keys[(((size_t)(b * N_ + n)) * L_ + s) * 256 + h * E_ + e];
        int col = ((((e >> 2) ^ (s & 7)) << 2) | (e & 3));
        qs_t[s][col] = qm[((size_t)b * 256 + h * E_ + e) * L_ + s];
    }
    __syncthreads();
    int tau = tid & 127, g = tid >> 7;
    double acc[8];
    #pragma unroll
    for (int i = 0; i < 8; ++i) acc[i] = 0.0;
    for (int s = 0; s < L_; ++s) {
        int t = (s + tau) & 127;
        float4 k0 = *(const float4*)&ks_t[s][g * 8];
        float4 k1 = *(const float4*)&ks_t[s][g * 8 + 4];
        float4 q0 = *(const float4*)&qs_t[t][((2 * g) ^ (t & 7)) << 2];
        float4 q1 = *(const float4*)&qs_t[t][((2 * g + 1) ^ (t & 7)) << 2];
        acc[0] = fma((double)k0.x, (double)q0.x, acc[0]);
        acc[1] = fma((double)k0.y, (double)q0.y, acc[1]);
        acc[2] = fma((double)k0.z, (double)q0.z, acc[2]);
        acc[3] = fma((double)k0.w, (double)q0.w, acc[3]);
        acc[4] = fma((double)k1.x, (double)q1.x, acc[4]);
        acc[5] = fma((double)k1.y, (double)q1.y, acc[5]);
        acc[6] = fma((double)k1.z, (double)q1.z, acc[6]);
        acc[7] = fma((double)k1.w, (double)q1.w, acc[7]);
    }
    vv[g][tau] = ((acc[0] + acc[1]) + (acc[2] + acc[3])) +
                 ((acc[4] + acc[5]) + (acc[6] + acc[7]));
    __syncthreads();
    if (tid < 64) {
        int lane = tid;
        float v0 = (float)((vv[0][lane] + vv[1][lane] + vv[2][lane] + vv[3][lane]) * (1.0 / 32.0));
        float v1 = (float)((vv[0][lane + 64] + vv[1][lane + 64] + vv[2][lane + 64] + vv[3][lane + 64]) * (1.0 / 32.0));

        float bv = v0; int bi = lane;
        if (v1 > v0) { bv = v1; bi = lane + 64; }
        #pragma unroll
        for (int m = 32; m; m >>= 1) {
            float ov = __shfl_xor(bv, m, 64);
            int   oi = __shfl_xor(bi, m, 64);
            if (ov > bv || (ov == bv && oi < bi)) { bv = ov; bi = oi; }
        }
        int i1 = bi; float w1v = bv;

        float c0 = (lane == i1) ? -INFINITY : v0;
        float c1 = (lane + 64 == i1) ? -INFINITY : v1;
        float bv2 = c0; int bi2 = lane;
        if (c1 > c0) { bv2 = c1; bi2 = lane + 64; }
        #pragma unroll
        for (int m = 32; m; m >>= 1) {
            float ov = __shfl_xor(bv2, m, 64);
            int   oi = __shfl_xor(bi2, m, 64);
            if (ov > bv2 || (ov == bv2 && oi < bi2)) { bv2 = ov; bi2 = oi; }
        }
        if (lane == 0) {
            didx[row * 2 + 0] = i1;
            didx[row * 2 + 1] = bi2;
            sig[row * 2 + 0] = 1.f / (1.f + expf(-w1v));
            sig[row * 2 + 1] = 1.f / (1.f + expf(-bv2));
        }
    }
}

// stable argsort by (delay asc, n asc) over N=64; emit sorted-order predecessors
__global__ __launch_bounds__(128) void k_sort(const int* __restrict__ didx,
                                              int* __restrict__ pred) {
    int bh = blockIdx.x;                // b*8+h
    int b = bh >> 3, h = bh & 7;
    int tid = threadIdx.x; int i = tid >> 6; int n = tid & 63;
    __shared__ int ds[2][64];
    __shared__ int pm[2][64];
    int d = 128 - didx[((b * 64 + n) * 8 + h) * 2 + i];
    ds[i][n] = d;
    __syncthreads();
    int rank = 0;
    for (int m = 0; m < 64; ++m) {
        int dm = ds[i][m];
        rank += (dm < d || (dm == d && m < n)) ? 1 : 0;
    }
    pm[i][rank] = n;
    __syncthreads();
    int p1v = (rank >= 1) ? pm[i][rank - 1] : -1;
    int p2v = (rank >= 2) ? pm[i][rank - 2] : -1;
    int o = ((bh * 2 + i) * 64 + n) * 2;
    pred[o] = p1v; pred[o + 1] = p2v;
}

// final gather: V[b,n,t,h,e] = 0.5 * sum_i [ b[c] + w2[c]*sig_n*v(n,t)
//   + w1[c]*sig_p1*v(p1,...) + w0[c]*sig_p2*v(p2,...) ]
__global__ __launch_bounds__(256) void k_out(const float* __restrict__ values,
                                             const float* __restrict__ wT,
                                             const float* __restrict__ bT,
                                             const int* __restrict__ didx,
                                             const float* __restrict__ sig,
                                             const int* __restrict__ pred,
                                             float* __restrict__ out) {
    int blk = blockIdx.x;               // (b*64+n)*8+h
    int h = blk & 7; int r = blk >> 3; int n = r & 63; int b = r >> 6;
    int tid = threadIdx.x; int e = tid & 31; int tr = tid >> 5;

    int di[2], dp1[2], dp2[2], p1[2], p2[2];
    float si[2], s1[2], s2[2];
    #pragma unroll
    for (int i = 0; i < 2; ++i) {
        di[i] = didx[blk * 2 + i];
        si[i] = sig[blk * 2 + i];
        int po = (((b * 8 + h) * 2 + i) * 64 + n) * 2;
        p1[i] = pred[po]; p2[i] = pred[po + 1];
        if (p1[i] >= 0) {
            int qidx = ((b * 64 + p1[i]) * 8 + h) * 2 + i;
            dp1[i] = didx[qidx]; s1[i] = sig[qidx];
        } else { dp1[i] = 0; s1[i] = 0.f; }
        if (p2[i] >= 0) {
            int qidx = ((b * 64 + p2[i]) * 8 + h) * 2 + i;
            dp2[i] = didx[qidx]; s2[i] = sig[qidx];
        } else { dp2[i] = 0; s2[i] = 0.f; }
    }
    const size_t vbase = ((size_t)b * N_) * L_ * 256 + h * E_ + e;
    const size_t obase = (((size_t)(b * N_ + n)) * L_) * 256 + h * E_ + e;

    for (int it = 0; it < 16; ++it) {
        int t = tr + 8 * it;
        float vself = values[vbase + ((size_t)n * L_ + t) * 256];
        float acc = 0.f;
        #pragma unroll
        for (int i = 0; i < 2; ++i) {
            int lp = (t + di[i]) & 127;
            int wo = lp * 32 + e;
            acc += bT[wo] + wT[8192 + wo] * si[i] * vself;
            if (p1[i] >= 0) {
                int t1 = (t + di[i] - dp1[i]) & 127;
                acc += wT[4096 + wo] * s1[i] * values[vbase + ((size_t)p1[i] * L_ + t1) * 256];
            }
            if (p2[i] >= 0) {
                int t2 = (t + di[i] - dp2[i]) & 127;
                acc += wT[wo] * s2[i] * values[vbase + ((size_t)p2[i] * L_ + t2) * 256];
            }
        }
        out[obase + (size_t)t * 256] = acc * 0.5f;
    }
}

extern "C" void kernel_launch(void* const* d_in, const int* in_sizes, int n_in,
                              void* d_out, int out_size, void* d_ws, size_t ws_size,
                              hipStream_t stream) {
    const float* queries = (const float*)d_in[0];
    const float* keys    = (const float*)d_in[1];
    const float* values  = (const float*)d_in[2];
    const float* w_cf = (const float*)d_in[4];
    const float* b_cf = (const float*)d_in[5];
    float* out = (float*)d_out;

    float* ws    = (float*)d_ws;
    float* qm    = ws;                    // 131072 f
    float* wT    = qm + 131072;           // 12288 f
    float* bT    = wT + 12288;            // 4096 f
    float* sigp  = bT + 4096;             // 4096 f
    int*   didxp = (int*)(sigp + 4096);   // 4096 i
    int*   predp = didxp + 4096;          // 8192 i
    int*   flags = predp + 8192;          // 2048 i

    // 8 MB of corr partials live in d_out (fully overwritten by k_out)
    float* part = (float*)d_out;

    k_qmean <<<512,  256, 0, stream>>>(queries, qm);
    k_prepwb<<<16,   256, 0, stream>>>(w_cf, b_cf, wT, bT);
    k_corr  <<<256,  512, 0, stream>>>(keys, qm, part);
    k_topk  <<<2048, 64,  0, stream>>>(part, didxp, sigp, flags);
    k_fixup <<<2048, 512, 0, stream>>>(keys, qm, flags, didxp, sigp);
    k_sort  <<<32,   128, 0, stream>>>(didxp, predp);
    k_out   <<<2048, 256, 0, stream>>>(values, wT, bT, didxp, sigp, predp, out);
}

// Round 5
// 97.933 us; speedup vs baseline: 1.7411x; 1.0249x over previous
//
#include <hip/hip_runtime.h>
#include <math.h>

#define B_ 4
#define N_ 64
#define L_ 128
#define H_ 8
#define E_ 32
#define SC_ 8

typedef __attribute__((ext_vector_type(8))) short short8;
typedef __attribute__((ext_vector_type(4))) float f32x4;

__device__ __forceinline__ unsigned short f2bf(float x) {
    union { float f; unsigned u; } c; c.f = x;
    unsigned r = (c.u + 0x7fffu + ((c.u >> 16) & 1u)) >> 16;
    return (unsigned short)r;
}
__device__ __forceinline__ float bf2f(unsigned short h) {
    union { unsigned u; float f; } c; c.u = ((unsigned)h) << 16;
    return c.f;
}

// qm[b][h][e][t] = mean over n of queries[b,n,t,h,e]   (fp64 accumulate)
__global__ __launch_bounds__(256) void k_qmean(const float* __restrict__ q,
                                               float* __restrict__ qm) {
    int blk = blockIdx.x;               // b*128 + t
    int b = blk >> 7, t = blk & 127;
    int c = threadIdx.x;                // h*32 + e
    const float* p = q + (((size_t)(b * N_)) * L_ + t) * 256 + c;
    double s = 0.0;
    for (int n = 0; n < N_; ++n) s += (double)p[(size_t)n * L_ * 256];
    qm[((size_t)b * 256 + c) * L_ + t] = (float)(s * (1.0 / 64.0));
}

// wT[dt][lp*32+e] = w_cf[(e*128+lp)*3 + dt],  bT[lp*32+e] = b_cf[e*128+lp]
__global__ void k_prepwb(const float* __restrict__ w, const float* __restrict__ bias,
                         float* __restrict__ wT, float* __restrict__ bT) {
    int k = blockIdx.x * 256 + threadIdx.x;  // 4096 = lp*32+e
    int e = k & 31, lp = k >> 5;
    int c = e * L_ + lp;
    wT[k]          = w[c * 3 + 0];
    wT[4096 + k]   = w[c * 3 + 1];
    wT[8192 + k]   = w[c * 3 + 2];
    bT[k]          = bias[c];
}

// MFMA corr: part[sc][b][n][h][tau] = sum_{s in chunk, e} keys[b,n,s,h,e]*qm[b,h,e,(s+tau)%128]
// split-bf16 (hi+lo, 3 MFMAs: hh + hl + lh), mfma_f32_16x16x32_bf16, K=32 = one s-plane.
__global__ __launch_bounds__(512) void k_corr(const float* __restrict__ keys,
                                              const float* __restrict__ qm,
                                              float* __restrict__ part) {
    int blk = blockIdx.x;
    int sc = blk & 7; int bh = blk >> 3; int h = bh & 7; int b = bh >> 3;
    __shared__ unsigned short Ahi[4][64][40];
    __shared__ unsigned short Alo[4][64][40];
    __shared__ unsigned short Qhi[128][40];
    __shared__ unsigned short Qlo[128][40];
    int tid = threadIdx.x;
    int lane = tid & 63, w = tid >> 6;
    int mg = w & 1, ng = w >> 1;

    {
        int e = tid >> 4; int tq = (tid & 15) * 4;
        const float* qp = qm + ((size_t)b * 256 + h * 32 + e) * 128;
        #pragma unroll
        for (int hf = 0; hf < 2; ++hf) {
            int t0 = tq + hf * 64;
            float4 v = *(const float4*)(qp + t0);
            float vv[4] = {v.x, v.y, v.z, v.w};
            #pragma unroll
            for (int j = 0; j < 4; ++j) {
                unsigned short hi = f2bf(vv[j]);
                Qhi[t0 + j][e] = hi;
                Qlo[t0 + j][e] = f2bf(vv[j] - bf2f(hi));
            }
        }
    }
    int sn = tid >> 3; int se = (tid & 7) * 4;
    const float* kbase = keys + ((size_t)(b * N_ + sn) * L_) * 256 + h * 32 + se;
    #pragma unroll
    for (int p = 0; p < 2; ++p) {
        float4 v = *(const float4*)(kbase + (size_t)(sc * 16 + p) * 256);
        float vv[4] = {v.x, v.y, v.z, v.w};
        ushort4 h4, l4;
        unsigned short* hp = (unsigned short*)&h4;
        unsigned short* lp = (unsigned short*)&l4;
        #pragma unroll
        for (int j = 0; j < 4; ++j) {
            hp[j] = f2bf(vv[j]);
            lp[j] = f2bf(vv[j] - bf2f(hp[j]));
        }
        *(ushort4*)&Ahi[p][sn][se] = h4;
        *(ushort4*)&Alo[p][sn][se] = l4;
    }
    __syncthreads();

    f32x4 acc[2][2];
    #pragma unroll
    for (int i = 0; i < 2; ++i)
        #pragma unroll
        for (int j = 0; j < 2; ++j)
            acc[i][j] = (f32x4){0.f, 0.f, 0.f, 0.f};

    int eb = (lane >> 4) * 8;
    int rA0 = (mg * 2) * 16 + (lane & 15);
    int rA1 = rA0 + 16;
    int tau0 = (ng * 2) * 16 + (lane & 15);
    int tau1 = tau0 + 16;

    for (int it = 0; it < 8; ++it) {
        float4 stg0, stg1;
        if (it < 7) {
            stg0 = *(const float4*)(kbase + (size_t)(sc * 16 + 2 * it + 2) * 256);
            stg1 = *(const float4*)(kbase + (size_t)(sc * 16 + 2 * it + 3) * 256);
        }
        #pragma unroll
        for (int sp = 0; sp < 2; ++sp) {
            int p = 2 * it + sp;
            int slot = p & 3;
            int s = sc * 16 + p;
            short8 ah0 = *(const short8*)&Ahi[slot][rA0][eb];
            short8 ah1 = *(const short8*)&Ahi[slot][rA1][eb];
            short8 al0 = *(const short8*)&Alo[slot][rA0][eb];
            short8 al1 = *(const short8*)&Alo[slot][rA1][eb];
            int t0 = (s + tau0) & 127;
            int t1 = (s + tau1) & 127;
            short8 bh0 = *(const short8*)&Qhi[t0][eb];
            short8 bh1 = *(const short8*)&Qhi[t1][eb];
            short8 bl0 = *(const short8*)&Qlo[t0][eb];
            short8 bl1 = *(const short8*)&Qlo[t1][eb];
            acc[0][0] = __builtin_amdgcn_mfma_f32_16x16x32_bf16(ah0, bh0, acc[0][0], 0, 0, 0);
            acc[0][1] = __builtin_amdgcn_mfma_f32_16x16x32_bf16(ah0, bh1, acc[0][1], 0, 0, 0);
            acc[1][0] = __builtin_amdgcn_mfma_f32_16x16x32_bf16(ah1, bh0, acc[1][0], 0, 0, 0);
            acc[1][1] = __builtin_amdgcn_mfma_f32_16x16x32_bf16(ah1, bh1, acc[1][1], 0, 0, 0);
            acc[0][0] = __builtin_amdgcn_mfma_f32_16x16x32_bf16(ah0, bl0, acc[0][0], 0, 0, 0);
            acc[0][1] = __builtin_amdgcn_mfma_f32_16x16x32_bf16(ah0, bl1, acc[0][1], 0, 0, 0);
            acc[1][0] = __builtin_amdgcn_mfma_f32_16x16x32_bf16(ah1, bl0, acc[1][0], 0, 0, 0);
            acc[1][1] = __builtin_amdgcn_mfma_f32_16x16x32_bf16(ah1, bl1, acc[1][1], 0, 0, 0);
            acc[0][0] = __builtin_amdgcn_mfma_f32_16x16x32_bf16(al0, bh0, acc[0][0], 0, 0, 0);
            acc[0][1] = __builtin_amdgcn_mfma_f32_16x16x32_bf16(al0, bh1, acc[0][1], 0, 0, 0);
            acc[1][0] = __builtin_amdgcn_mfma_f32_16x16x32_bf16(al1, bh0, acc[1][0], 0, 0, 0);
            acc[1][1] = __builtin_amdgcn_mfma_f32_16x16x32_bf16(al1, bh1, acc[1][1], 0, 0, 0);
        }
        if (it < 7) {
            #pragma unroll
            for (int sp = 0; sp < 2; ++sp) {
                int p = 2 * it + 2 + sp;
                int slot = p & 3;
                float4 v = sp ? stg1 : stg0;
                float vv[4] = {v.x, v.y, v.z, v.w};
                ushort4 h4, l4;
                unsigned short* hp = (unsigned short*)&h4;
                unsigned short* lp = (unsigned short*)&l4;
                #pragma unroll
                for (int j = 0; j < 4; ++j) {
                    hp[j] = f2bf(vv[j]);
                    lp[j] = f2bf(vv[j] - bf2f(hp[j]));
                }
                *(ushort4*)&Ahi[slot][sn][se] = h4;
                *(ushort4*)&Alo[slot][sn][se] = l4;
            }
        }
        __syncthreads();
    }

    #pragma unroll
    for (int i = 0; i < 2; ++i) {
        int mt = mg * 2 + i;
        #pragma unroll
        for (int j = 0; j < 2; ++j) {
            int nt = ng * 2 + j;
            int tau = nt * 16 + (lane & 15);
            #pragma unroll
            for (int r = 0; r < 4; ++r) {
                int n = mt * 16 + (lane >> 4) * 4 + r;
                part[((((size_t)sc * B_ + b) * N_ + n) * H_ + h) * L_ + tau] = acc[i][j][r];
            }
        }
    }
}

// top-2 over tau per (b,n,h) + near-tie flag (v2 - v3 < margin)
__global__ __launch_bounds__(64) void k_topk(const float* __restrict__ part,
                                             int* __restrict__ didx,
                                             float* __restrict__ sig,
                                             int* __restrict__ flags) {
    int blk = blockIdx.x;               // (b*64+n)*8+h
    int lane = threadIdx.x;
    size_t rb = (size_t)blk * L_;
    const size_t stride = (size_t)B_ * N_ * H_ * L_;
    double s0 = 0.0, s1 = 0.0;
    for (int sc = 0; sc < SC_; ++sc) {
        s0 += (double)part[sc * stride + rb + lane];
        s1 += (double)part[sc * stride + rb + lane + 64];
    }
    float v0 = (float)(s0 * (1.0 / 32.0));
    float v1 = (float)(s1 * (1.0 / 32.0));

    float bv = v0; int bi = lane;
    if (v1 > v0) { bv = v1; bi = lane + 64; }
    #pragma unroll
    for (int m = 32; m; m >>= 1) {
        float ov = __shfl_xor(bv, m, 64);
        int   oi = __shfl_xor(bi, m, 64);
        if (ov > bv || (ov == bv && oi < bi)) { bv = ov; bi = oi; }
    }
    int i1 = bi; float w1v = bv;

    float c0 = (lane == i1) ? -INFINITY : v0;
    float c1 = (lane + 64 == i1) ? -INFINITY : v1;
    float bv2 = c0; int bi2 = lane;
    if (c1 > c0) { bv2 = c1; bi2 = lane + 64; }
    #pragma unroll
    for (int m = 32; m; m >>= 1) {
        float ov = __shfl_xor(bv2, m, 64);
        int   oi = __shfl_xor(bi2, m, 64);
        if (ov > bv2 || (ov == bv2 && oi < bi2)) { bv2 = ov; bi2 = oi; }
    }
    int i2 = bi2; float w2v = bv2;

    float d0 = (lane == i1 || lane == i2) ? -INFINITY : v0;
    float d1 = (lane + 64 == i1 || lane + 64 == i2) ? -INFINITY : v1;
    float bv3 = fmaxf(d0, d1);
    #pragma unroll
    for (int m = 32; m; m >>= 1) bv3 = fmaxf(bv3, __shfl_xor(bv3, m, 64));

    if (lane == 0) {
        didx[blk * 2 + 0] = i1;
        didx[blk * 2 + 1] = i2;
        sig[blk * 2 + 0] = 1.f / (1.f + expf(-w1v));
        sig[blk * 2 + 1] = 1.f / (1.f + expf(-w2v));
        flags[blk] = (w2v - bv3 < 1e-3f) ? 1 : 0;
    }
}

// exact fp64 recompute of flagged rows; overwrites didx/sig (jax tie semantics).
__global__ __launch_bounds__(512) void k_fixup(const float* __restrict__ keys,
                                               const float* __restrict__ qm,
                                               const int* __restrict__ flags,
                                               int* __restrict__ didx,
                                               float* __restrict__ sig) {
    int row = blockIdx.x;               // (b*64+n)*8+h
    if (!flags[row]) return;
    int h = row & 7; int r = row >> 3; int n = r & 63; int b = r >> 6;
    __shared__ float ks_t[L_][E_];
    __shared__ float qs_t[L_][E_];
    __shared__ double vv[4][L_];
    int tid = threadIdx.x;
    for (int k = tid; k < E_ * L_; k += 512) {
        int e = k & 31; int s = k >> 5;
        ks_t[s][e] = keys[(((size_t)(b * N_ + n)) * L_ + s) * 256 + h * E_ + e];
        int col = ((((e >> 2) ^ (s & 7)) << 2) | (e & 3));
        qs_t[s][col] = qm[((size_t)b * 256 + h * E_ + e) * L_ + s];
    }
    __syncthreads();
    int tau = tid & 127, g = tid >> 7;
    double acc[8];
    #pragma unroll
    for (int i = 0; i < 8; ++i) acc[i] = 0.0;
    for (int s = 0; s < L_; ++s) {
        int t = (s + tau) & 127;
        float4 k0 = *(const float4*)&ks_t[s][g * 8];
        float4 k1 = *(const float4*)&ks_t[s][g * 8 + 4];
        float4 q0 = *(const float4*)&qs_t[t][((2 * g) ^ (t & 7)) << 2];
        float4 q1 = *(const float4*)&qs_t[t][((2 * g + 1) ^ (t & 7)) << 2];
        acc[0] = fma((double)k0.x, (double)q0.x, acc[0]);
        acc[1] = fma((double)k0.y, (double)q0.y, acc[1]);
        acc[2] = fma((double)k0.z, (double)q0.z, acc[2]);
        acc[3] = fma((double)k0.w, (double)q0.w, acc[3]);
        acc[4] = fma((double)k1.x, (double)q1.x, acc[4]);
        acc[5] = fma((double)k1.y, (double)q1.y, acc[5]);
        acc[6] = fma((double)k1.z, (double)q1.z, acc[6]);
        acc[7] = fma((double)k1.w, (double)q1.w, acc[7]);
    }
    vv[g][tau] = ((acc[0] + acc[1]) + (acc[2] + acc[3])) +
                 ((acc[4] + acc[5]) + (acc[6] + acc[7]));
    __syncthreads();
    if (tid < 64) {
        int lane = tid;
        float v0 = (float)((vv[0][lane] + vv[1][lane] + vv[2][lane] + vv[3][lane]) * (1.0 / 32.0));
        float v1 = (float)((vv[0][lane + 64] + vv[1][lane + 64] + vv[2][lane + 64] + vv[3][lane + 64]) * (1.0 / 32.0));

        float bv = v0; int bi = lane;
        if (v1 > v0) { bv = v1; bi = lane + 64; }
        #pragma unroll
        for (int m = 32; m; m >>= 1) {
            float ov = __shfl_xor(bv, m, 64);
            int   oi = __shfl_xor(bi, m, 64);
            if (ov > bv || (ov == bv && oi < bi)) { bv = ov; bi = oi; }
        }
        int i1 = bi; float w1v = bv;

        float c0 = (lane == i1) ? -INFINITY : v0;
        float c1 = (lane + 64 == i1) ? -INFINITY : v1;
        float bv2 = c0; int bi2 = lane;
        if (c1 > c0) { bv2 = c1; bi2 = lane + 64; }
        #pragma unroll
        for (int m = 32; m; m >>= 1) {
            float ov = __shfl_xor(bv2, m, 64);
            int   oi = __shfl_xor(bi2, m, 64);
            if (ov > bv2 || (ov == bv2 && oi < bi2)) { bv2 = ov; bi2 = oi; }
        }
        if (lane == 0) {
            didx[row * 2 + 0] = i1;
            didx[row * 2 + 1] = bi2;
            sig[row * 2 + 0] = 1.f / (1.f + expf(-w1v));
            sig[row * 2 + 1] = 1.f / (1.f + expf(-bv2));
        }
    }
}

// stable argsort by (delay asc, n asc) over N=64; emit sorted-order predecessors
__global__ __launch_bounds__(128) void k_sort(const int* __restrict__ didx,
                                              int* __restrict__ pred) {
    int bh = blockIdx.x;                // b*8+h
    int b = bh >> 3, h = bh & 7;
    int tid = threadIdx.x; int i = tid >> 6; int n = tid & 63;
    __shared__ int ds[2][64];
    __shared__ int pm[2][64];
    int d = 128 - didx[((b * 64 + n) * 8 + h) * 2 + i];
    ds[i][n] = d;
    __syncthreads();
    int rank = 0;
    for (int m = 0; m < 64; ++m) {
        int dm = ds[i][m];
        rank += (dm < d || (dm == d && m < n)) ? 1 : 0;
    }
    pm[i][rank] = n;
    __syncthreads();
    int p1v = (rank >= 1) ? pm[i][rank - 1] : -1;
    int p2v = (rank >= 2) ? pm[i][rank - 2] : -1;
    int o = ((bh * 2 + i) * 64 + n) * 2;
    pred[o] = p1v; pred[o + 1] = p2v;
}

// final gather, float4 over e + LDS-staged weights.
// V[b,n,t,h,:] = 0.5 * sum_i [ b + w2*sig_n*v(n,t) + w1*s1*v(p1,t1) + w0*s2*v(p2,t2) ]
__global__ __launch_bounds__(256) void k_out(const float* __restrict__ values,
                                             const float* __restrict__ wT,
                                             const float* __restrict__ bT,
                                             const int* __restrict__ didx,
                                             const float* __restrict__ sig,
                                             const int* __restrict__ pred,
                                             float* __restrict__ out) {
    int blk = blockIdx.x;               // (b*64+n)*8+h
    int h = blk & 7; int r = blk >> 3; int n = r & 63; int b = r >> 6;
    int tid = threadIdx.x; int e4 = tid & 7; int tq = tid >> 3;

    __shared__ f32x4 wL[3][128][8];     // 48 KB
    __shared__ f32x4 bL[128][8];        // 16 KB
    {
        const f32x4* wTv = (const f32x4*)wT;
        const f32x4* bTv = (const f32x4*)bT;
        f32x4* wd = &wL[0][0][0];
        #pragma unroll
        for (int k = 0; k < 12; ++k) wd[k * 256 + tid] = wTv[k * 256 + tid];
        f32x4* bd = &bL[0][0];
        #pragma unroll
        for (int k = 0; k < 4; ++k) bd[k * 256 + tid] = bTv[k * 256 + tid];
    }

    int di[2], dp1[2], dp2[2], p1[2], p2[2];
    float si[2], s1[2], s2[2];
    #pragma unroll
    for (int i = 0; i < 2; ++i) {
        di[i] = didx[blk * 2 + i];
        si[i] = sig[blk * 2 + i];
        int po = (((b * 8 + h) * 2 + i) * 64 + n) * 2;
        p1[i] = pred[po]; p2[i] = pred[po + 1];
        if (p1[i] >= 0) {
            int qidx = ((b * 64 + p1[i]) * 8 + h) * 2 + i;
            dp1[i] = didx[qidx]; s1[i] = sig[qidx];
        } else { dp1[i] = 0; s1[i] = 0.f; }
        if (p2[i] >= 0) {
            int qidx = ((b * 64 + p2[i]) * 8 + h) * 2 + i;
            dp2[i] = didx[qidx]; s2[i] = sig[qidx];
        } else { dp2[i] = 0; s2[i] = 0.f; }
    }
    __syncthreads();

    const f32x4* v4 = (const f32x4*)values;
    f32x4* o4 = (f32x4*)out;
    // float4-index of (n', t'): base + (n'*128 + t')*64
    const size_t base = ((size_t)b * N_) * L_ * 64 + h * 8 + e4;

    #pragma unroll
    for (int it = 0; it < 4; ++it) {
        int t = tq + 32 * it;
        f32x4 vs = v4[base + ((size_t)n * L_ + t) * 64];
        f32x4 acc = (f32x4){0.f, 0.f, 0.f, 0.f};
        #pragma unroll
        for (int i = 0; i < 2; ++i) {
            int lp = (t + di[i]) & 127;
            acc += bL[lp][e4] + wL[2][lp][e4] * (si[i] * vs);
            if (p1[i] >= 0) {
                int t1 = (t + di[i] - dp1[i]) & 127;
                f32x4 vv = v4[base + ((size_t)p1[i] * L_ + t1) * 64];
                acc += wL[1][lp][e4] * (s1[i] * vv);
            }
            if (p2[i] >= 0) {
                int t2 = (t + di[i] - dp2[i]) & 127;
                f32x4 vv = v4[base + ((size_t)p2[i] * L_ + t2) * 64];
                acc += wL[0][lp][e4] * (s2[i] * vv);
            }
        }
        o4[base + ((size_t)n * L_ + t) * 64] = acc * 0.5f;
    }
}

extern "C" void kernel_launch(void* const* d_in, const int* in_sizes, int n_in,
                              void* d_out, int out_size, void* d_ws, size_t ws_size,
                              hipStream_t stream) {
    const float* queries = (const float*)d_in[0];
    const float* keys    = (const float*)d_in[1];
    const float* values  = (const float*)d_in[2];
    const float* w_cf = (const float*)d_in[4];
    const float* b_cf = (const float*)d_in[5];
    float* out = (float*)d_out;

    float* ws    = (float*)d_ws;
    float* qm    = ws;                    // 131072 f
    float* wT    = qm + 131072;           // 12288 f
    float* bT    = wT + 12288;            // 4096 f
    float* sigp  = bT + 4096;             // 4096 f
    int*   didxp = (int*)(sigp + 4096);   // 4096 i
    int*   predp = didxp + 4096;          // 8192 i
    int*   flags = predp + 8192;          // 2048 i

    // 8 MB of corr partials live in d_out (fully overwritten by k_out)
    float* part = (float*)d_out;

    k_qmean <<<512,  256, 0, stream>>>(queries, qm);
    k_prepwb<<<16,   256, 0, stream>>>(w_cf, b_cf, wT, bT);
    k_corr  <<<256,  512, 0, stream>>>(keys, qm, part);
    k_topk  <<<2048, 64,  0, stream>>>(part, didxp, sigp, flags);
    k_fixup <<<2048, 512, 0, stream>>>(keys, qm, flags, didxp, sigp);
    k_sort  <<<32,   128, 0, stream>>>(didxp, predp);
    k_out   <<<2048, 256, 0, stream>>>(values, wT, bT, didxp, sigp, predp, out);
}

// Round 6
// 89.953 us; speedup vs baseline: 1.8955x; 1.0887x over previous
//
#include <hip/hip_runtime.h>
#include <math.h>

#define B_ 4
#define N_ 64
#define L_ 128
#define H_ 8
#define E_ 32
#define SC_ 8

typedef __attribute__((ext_vector_type(8))) short short8;
typedef __attribute__((ext_vector_type(4))) float f32x4;

__device__ __forceinline__ unsigned short f2bf(float x) {
    union { float f; unsigned u; } c; c.f = x;
    unsigned r = (c.u + 0x7fffu + ((c.u >> 16) & 1u)) >> 16;
    return (unsigned short)r;
}
__device__ __forceinline__ float bf2f(unsigned short h) {
    union { unsigned u; float f; } c; c.u = ((unsigned)h) << 16;
    return c.f;
}

// qm[b][h][e][t] = mean over n of queries[b,n,t,h,e]   (fp64 accumulate)
__global__ __launch_bounds__(256) void k_qmean(const float* __restrict__ q,
                                               float* __restrict__ qm) {
    int blk = blockIdx.x;               // b*128 + t
    int b = blk >> 7, t = blk & 127;
    int c = threadIdx.x;                // h*32 + e
    const float* p = q + (((size_t)(b * N_)) * L_ + t) * 256 + c;
    double s = 0.0;
    for (int n = 0; n < N_; ++n) s += (double)p[(size_t)n * L_ * 256];
    qm[((size_t)b * 256 + c) * L_ + t] = (float)(s * (1.0 / 64.0));
}

// wT[dt][lp*32+e] = w_cf[(e*128+lp)*3 + dt],  bT[lp*32+e] = b_cf[e*128+lp]
__global__ void k_prepwb(const float* __restrict__ w, const float* __restrict__ bias,
                         float* __restrict__ wT, float* __restrict__ bT) {
    int k = blockIdx.x * 256 + threadIdx.x;  // 4096 = lp*32+e
    int e = k & 31, lp = k >> 5;
    int c = e * L_ + lp;
    wT[k]          = w[c * 3 + 0];
    wT[4096 + k]   = w[c * 3 + 1];
    wT[8192 + k]   = w[c * 3 + 2];
    bT[k]          = bias[c];
}

// MFMA corr: part[sc][b][n][h][tau] = sum_{s in chunk, e} keys[b,n,s,h,e]*qm[b,h,e,(s+tau)%128]
// split-bf16 (hi+lo, 3 MFMAs: hh + hl + lh), mfma_f32_16x16x32_bf16, K=32 = one s-plane.
__global__ __launch_bounds__(512) void k_corr(const float* __restrict__ keys,
                                              const float* __restrict__ qm,
                                              float* __restrict__ part) {
    int blk = blockIdx.x;
    int sc = blk & 7; int bh = blk >> 3; int h = bh & 7; int b = bh >> 3;
    __shared__ unsigned short Ahi[4][64][40];
    __shared__ unsigned short Alo[4][64][40];
    __shared__ unsigned short Qhi[128][40];
    __shared__ unsigned short Qlo[128][40];
    int tid = threadIdx.x;
    int lane = tid & 63, w = tid >> 6;
    int mg = w & 1, ng = w >> 1;

    {
        int e = tid >> 4; int tq = (tid & 15) * 4;
        const float* qp = qm + ((size_t)b * 256 + h * 32 + e) * 128;
        #pragma unroll
        for (int hf = 0; hf < 2; ++hf) {
            int t0 = tq + hf * 64;
            float4 v = *(const float4*)(qp + t0);
            float vv[4] = {v.x, v.y, v.z, v.w};
            #pragma unroll
            for (int j = 0; j < 4; ++j) {
                unsigned short hi = f2bf(vv[j]);
                Qhi[t0 + j][e] = hi;
                Qlo[t0 + j][e] = f2bf(vv[j] - bf2f(hi));
            }
        }
    }
    int sn = tid >> 3; int se = (tid & 7) * 4;
    const float* kbase = keys + ((size_t)(b * N_ + sn) * L_) * 256 + h * 32 + se;
    #pragma unroll
    for (int p = 0; p < 2; ++p) {
        float4 v = *(const float4*)(kbase + (size_t)(sc * 16 + p) * 256);
        float vv[4] = {v.x, v.y, v.z, v.w};
        ushort4 h4, l4;
        unsigned short* hp = (unsigned short*)&h4;
        unsigned short* lp = (unsigned short*)&l4;
        #pragma unroll
        for (int j = 0; j < 4; ++j) {
            hp[j] = f2bf(vv[j]);
            lp[j] = f2bf(vv[j] - bf2f(hp[j]));
        }
        *(ushort4*)&Ahi[p][sn][se] = h4;
        *(ushort4*)&Alo[p][sn][se] = l4;
    }
    __syncthreads();

    f32x4 acc[2][2];
    #pragma unroll
    for (int i = 0; i < 2; ++i)
        #pragma unroll
        for (int j = 0; j < 2; ++j)
            acc[i][j] = (f32x4){0.f, 0.f, 0.f, 0.f};

    int eb = (lane >> 4) * 8;
    int rA0 = (mg * 2) * 16 + (lane & 15);
    int rA1 = rA0 + 16;
    int tau0 = (ng * 2) * 16 + (lane & 15);
    int tau1 = tau0 + 16;

    for (int it = 0; it < 8; ++it) {
        float4 stg0, stg1;
        if (it < 7) {
            stg0 = *(const float4*)(kbase + (size_t)(sc * 16 + 2 * it + 2) * 256);
            stg1 = *(const float4*)(kbase + (size_t)(sc * 16 + 2 * it + 3) * 256);
        }
        #pragma unroll
        for (int sp = 0; sp < 2; ++sp) {
            int p = 2 * it + sp;
            int slot = p & 3;
            int s = sc * 16 + p;
            short8 ah0 = *(const short8*)&Ahi[slot][rA0][eb];
            short8 ah1 = *(const short8*)&Ahi[slot][rA1][eb];
            short8 al0 = *(const short8*)&Alo[slot][rA0][eb];
            short8 al1 = *(const short8*)&Alo[slot][rA1][eb];
            int t0 = (s + tau0) & 127;
            int t1 = (s + tau1) & 127;
            short8 bh0 = *(const short8*)&Qhi[t0][eb];
            short8 bh1 = *(const short8*)&Qhi[t1][eb];
            short8 bl0 = *(const short8*)&Qlo[t0][eb];
            short8 bl1 = *(const short8*)&Qlo[t1][eb];
            acc[0][0] = __builtin_amdgcn_mfma_f32_16x16x32_bf16(ah0, bh0, acc[0][0], 0, 0, 0);
            acc[0][1] = __builtin_amdgcn_mfma_f32_16x16x32_bf16(ah0, bh1, acc[0][1], 0, 0, 0);
            acc[1][0] = __builtin_amdgcn_mfma_f32_16x16x32_bf16(ah1, bh0, acc[1][0], 0, 0, 0);
            acc[1][1] = __builtin_amdgcn_mfma_f32_16x16x32_bf16(ah1, bh1, acc[1][1], 0, 0, 0);
            acc[0][0] = __builtin_amdgcn_mfma_f32_16x16x32_bf16(ah0, bl0, acc[0][0], 0, 0, 0);
            acc[0][1] = __builtin_amdgcn_mfma_f32_16x16x32_bf16(ah0, bl1, acc[0][1], 0, 0, 0);
            acc[1][0] = __builtin_amdgcn_mfma_f32_16x16x32_bf16(ah1, bl0, acc[1][0], 0, 0, 0);
            acc[1][1] = __builtin_amdgcn_mfma_f32_16x16x32_bf16(ah1, bl1, acc[1][1], 0, 0, 0);
            acc[0][0] = __builtin_amdgcn_mfma_f32_16x16x32_bf16(al0, bh0, acc[0][0], 0, 0, 0);
            acc[0][1] = __builtin_amdgcn_mfma_f32_16x16x32_bf16(al0, bh1, acc[0][1], 0, 0, 0);
            acc[1][0] = __builtin_amdgcn_mfma_f32_16x16x32_bf16(al1, bh0, acc[1][0], 0, 0, 0);
            acc[1][1] = __builtin_amdgcn_mfma_f32_16x16x32_bf16(al1, bh1, acc[1][1], 0, 0, 0);
        }
        if (it < 7) {
            #pragma unroll
            for (int sp = 0; sp < 2; ++sp) {
                int p = 2 * it + 2 + sp;
                int slot = p & 3;
                float4 v = sp ? stg1 : stg0;
                float vv[4] = {v.x, v.y, v.z, v.w};
                ushort4 h4, l4;
                unsigned short* hp = (unsigned short*)&h4;
                unsigned short* lp = (unsigned short*)&l4;
                #pragma unroll
                for (int j = 0; j < 4; ++j) {
                    hp[j] = f2bf(vv[j]);
                    lp[j] = f2bf(vv[j] - bf2f(hp[j]));
                }
                *(ushort4*)&Ahi[slot][sn][se] = h4;
                *(ushort4*)&Alo[slot][sn][se] = l4;
            }
        }
        __syncthreads();
    }

    #pragma unroll
    for (int i = 0; i < 2; ++i) {
        int mt = mg * 2 + i;
        #pragma unroll
        for (int j = 0; j < 2; ++j) {
            int nt = ng * 2 + j;
            int tau = nt * 16 + (lane & 15);
            #pragma unroll
            for (int r = 0; r < 4; ++r) {
                int n = mt * 16 + (lane >> 4) * 4 + r;
                part[((((size_t)sc * B_ + b) * N_ + n) * H_ + h) * L_ + tau] = acc[i][j][r];
            }
        }
    }
}

// top-2 over tau per (b,n,h) + near-tie flag (v2 - v3 < margin)
__global__ __launch_bounds__(64) void k_topk(const float* __restrict__ part,
                                             int* __restrict__ didx,
                                             float* __restrict__ sig,
                                             int* __restrict__ flags) {
    int blk = blockIdx.x;               // (b*64+n)*8+h
    int lane = threadIdx.x;
    size_t rb = (size_t)blk * L_;
    const size_t stride = (size_t)B_ * N_ * H_ * L_;
    double s0 = 0.0, s1 = 0.0;
    for (int sc = 0; sc < SC_; ++sc) {
        s0 += (double)part[sc * stride + rb + lane];
        s1 += (double)part[sc * stride + rb + lane + 64];
    }
    float v0 = (float)(s0 * (1.0 / 32.0));
    float v1 = (float)(s1 * (1.0 / 32.0));

    float bv = v0; int bi = lane;
    if (v1 > v0) { bv = v1; bi = lane + 64; }
    #pragma unroll
    for (int m = 32; m; m >>= 1) {
        float ov = __shfl_xor(bv, m, 64);
        int   oi = __shfl_xor(bi, m, 64);
        if (ov > bv || (ov == bv && oi < bi)) { bv = ov; bi = oi; }
    }
    int i1 = bi; float w1v = bv;

    float c0 = (lane == i1) ? -INFINITY : v0;
    float c1 = (lane + 64 == i1) ? -INFINITY : v1;
    float bv2 = c0; int bi2 = lane;
    if (c1 > c0) { bv2 = c1; bi2 = lane + 64; }
    #pragma unroll
    for (int m = 32; m; m >>= 1) {
        float ov = __shfl_xor(bv2, m, 64);
        int   oi = __shfl_xor(bi2, m, 64);
        if (ov > bv2 || (ov == bv2 && oi < bi2)) { bv2 = ov; bi2 = oi; }
    }
    int i2 = bi2; float w2v = bv2;

    float d0 = (lane == i1 || lane == i2) ? -INFINITY : v0;
    float d1 = (lane + 64 == i1 || lane + 64 == i2) ? -INFINITY : v1;
    float bv3 = fmaxf(d0, d1);
    #pragma unroll
    for (int m = 32; m; m >>= 1) bv3 = fmaxf(bv3, __shfl_xor(bv3, m, 64));

    if (lane == 0) {
        didx[blk * 2 + 0] = i1;
        didx[blk * 2 + 1] = i2;
        sig[blk * 2 + 0] = 1.f / (1.f + expf(-w1v));
        sig[blk * 2 + 1] = 1.f / (1.f + expf(-w2v));
        flags[blk] = (w2v - bv3 < 1e-3f) ? 1 : 0;
    }
}

// exact fp64 recompute of flagged rows; overwrites didx/sig (jax tie semantics).
// named-scalar accumulators (NO arrays -> no scratch spill), 512 thr = 128 tau x 4 e-grp.
__global__ __launch_bounds__(512, 2) void k_fixup(const float* __restrict__ keys,
                                                  const float* __restrict__ qm,
                                                  const int* __restrict__ flags,
                                                  int* __restrict__ didx,
                                                  float* __restrict__ sig) {
    int row = blockIdx.x;               // (b*64+n)*8+h
    if (!flags[row]) return;
    int h = row & 7; int r = row >> 3; int n = r & 63; int b = r >> 6;
    __shared__ float ks_t[L_][E_];
    __shared__ float qs_t[L_][E_];
    __shared__ double vv[4][L_];
    int tid = threadIdx.x;
    for (int k = tid; k < E_ * L_; k += 512) {
        int e = k & 31; int s = k >> 5;
        ks_t[s][e] = keys[(((size_t)(b * N_ + n)) * L_ + s) * 256 + h * E_ + e];
        int col = ((((e >> 2) ^ (s & 7)) << 2) | (e & 3));
        qs_t[s][col] = qm[((size_t)b * 256 + h * E_ + e) * L_ + s];
    }
    __syncthreads();
    int tau = tid & 127, g = tid >> 7;
    double a0 = 0, a1 = 0, a2 = 0, a3 = 0, a4 = 0, a5 = 0, a6 = 0, a7 = 0;
    #pragma unroll 4
    for (int s = 0; s < L_; ++s) {
        int t = (s + tau) & 127;
        float4 k0 = *(const float4*)&ks_t[s][g * 8];
        float4 k1 = *(const float4*)&ks_t[s][g * 8 + 4];
        float4 q0 = *(const float4*)&qs_t[t][((2 * g) ^ (t & 7)) << 2];
        float4 q1 = *(const float4*)&qs_t[t][((2 * g + 1) ^ (t & 7)) << 2];
        a0 = fma((double)k0.x, (double)q0.x, a0);
        a1 = fma((double)k0.y, (double)q0.y, a1);
        a2 = fma((double)k0.z, (double)q0.z, a2);
        a3 = fma((double)k0.w, (double)q0.w, a3);
        a4 = fma((double)k1.x, (double)q1.x, a4);
        a5 = fma((double)k1.y, (double)q1.y, a5);
        a6 = fma((double)k1.z, (double)q1.z, a6);
        a7 = fma((double)k1.w, (double)q1.w, a7);
    }
    vv[g][tau] = ((a0 + a1) + (a2 + a3)) + ((a4 + a5) + (a6 + a7));
    __syncthreads();
    if (tid < 64) {
        int lane = tid;
        float v0 = (float)((vv[0][lane] + vv[1][lane] + vv[2][lane] + vv[3][lane]) * (1.0 / 32.0));
        float v1 = (float)((vv[0][lane + 64] + vv[1][lane + 64] + vv[2][lane + 64] + vv[3][lane + 64]) * (1.0 / 32.0));

        float bv = v0; int bi = lane;
        if (v1 > v0) { bv = v1; bi = lane + 64; }
        #pragma unroll
        for (int m = 32; m; m >>= 1) {
            float ov = __shfl_xor(bv, m, 64);
            int   oi = __shfl_xor(bi, m, 64);
            if (ov > bv || (ov == bv && oi < bi)) { bv = ov; bi = oi; }
        }
        int i1 = bi; float w1v = bv;

        float c0 = (lane == i1) ? -INFINITY : v0;
        float c1 = (lane + 64 == i1) ? -INFINITY : v1;
        float bv2 = c0; int bi2 = lane;
        if (c1 > c0) { bv2 = c1; bi2 = lane + 64; }
        #pragma unroll
        for (int m = 32; m; m >>= 1) {
            float ov = __shfl_xor(bv2, m, 64);
            int   oi = __shfl_xor(bi2, m, 64);
            if (ov > bv2 || (ov == bv2 && oi < bi2)) { bv2 = ov; bi2 = oi; }
        }
        if (lane == 0) {
            didx[row * 2 + 0] = i1;
            didx[row * 2 + 1] = bi2;
            sig[row * 2 + 0] = 1.f / (1.f + expf(-w1v));
            sig[row * 2 + 1] = 1.f / (1.f + expf(-bv2));
        }
    }
}

// stable argsort by (delay asc, n asc) over N=64; emit sorted-order predecessors
__global__ __launch_bounds__(128) void k_sort(const int* __restrict__ didx,
                                              int* __restrict__ pred) {
    int bh = blockIdx.x;                // b*8+h
    int b = bh >> 3, h = bh & 7;
    int tid = threadIdx.x; int i = tid >> 6; int n = tid & 63;
    __shared__ int ds[2][64];
    __shared__ int pm[2][64];
    int d = 128 - didx[((b * 64 + n) * 8 + h) * 2 + i];
    ds[i][n] = d;
    __syncthreads();
    int rank = 0;
    for (int m = 0; m < 64; ++m) {
        int dm = ds[i][m];
        rank += (dm < d || (dm == d && m < n)) ? 1 : 0;
    }
    pm[i][rank] = n;
    __syncthreads();
    int p1v = (rank >= 1) ? pm[i][rank - 1] : -1;
    int p2v = (rank >= 2) ? pm[i][rank - 2] : -1;
    int o = ((bh * 2 + i) * 64 + n) * 2;
    pred[o] = p1v; pred[o + 1] = p2v;
}

// final gather v3: branch-free, all value-gathers + weight reads preloaded into
// registers (one counted-vmcnt batch), no LDS. grid 4096 = blk*2+half, 256 thr.
__global__ __launch_bounds__(256, 2) void k_out(const float* __restrict__ values,
                                                const float* __restrict__ wT,
                                                const float* __restrict__ bT,
                                                const int* __restrict__ didx,
                                                const float* __restrict__ sig,
                                                const int* __restrict__ pred,
                                                float* __restrict__ out) {
    int bid = blockIdx.x;
    int half = bid & 1; int blk = bid >> 1;   // (b*64+n)*8+h
    int h = blk & 7; int r = blk >> 3; int n = r & 63; int b = r >> 6;
    int tid = threadIdx.x; int e4 = tid & 7; int tq = tid >> 3;  // tq 0..31

    int di[2]; float si[2];
    int pq1[2], pq2[2], dq1[2], dq2[2]; float s1[2], s2[2];
    #pragma unroll
    for (int i = 0; i < 2; ++i) {
        di[i] = didx[blk * 2 + i];
        si[i] = sig[blk * 2 + i];
        int po = (((b * 8 + h) * 2 + i) * 64 + n) * 2;
        int p1 = pred[po], p2 = pred[po + 1];
        if (p1 >= 0) { int q = ((b * 64 + p1) * 8 + h) * 2 + i; pq1[i] = p1; dq1[i] = didx[q]; s1[i] = sig[q]; }
        else         { pq1[i] = n; dq1[i] = di[i]; s1[i] = 0.f; }
        if (p2 >= 0) { int q = ((b * 64 + p2) * 8 + h) * 2 + i; pq2[i] = p2; dq2[i] = didx[q]; s2[i] = sig[q]; }
        else         { pq2[i] = n; dq2[i] = di[i]; s2[i] = 0.f; }
    }
    const f32x4* v4 = (const f32x4*)values;
    const f32x4* w4 = (const f32x4*)wT;
    const f32x4* b4 = (const f32x4*)bT;
    f32x4* o4 = (f32x4*)out;
    const size_t base = ((size_t)b * N_) * L_ * 64 + h * 8 + e4;

    // ---- batch 1: all value gathers (branch-free, 10 independent b128 loads)
    f32x4 vs[2], va1[2], va2[2], vb1[2], vb2[2];
    int lp0[2], lp1[2];
    #pragma unroll
    for (int it = 0; it < 2; ++it) {
        int t = half * 64 + tq + 32 * it;
        vs[it] = v4[base + ((size_t)n * L_ + t) * 64];
        int ta1 = (t + di[0] - dq1[0]) & 127;
        va1[it] = v4[base + ((size_t)pq1[0] * L_ + ta1) * 64];
        int ta2 = (t + di[0] - dq2[0]) & 127;
        va2[it] = v4[base + ((size_t)pq2[0] * L_ + ta2) * 64];
        int tb1 = (t + di[1] - dq1[1]) & 127;
        vb1[it] = v4[base + ((size_t)pq1[1] * L_ + tb1) * 64];
        int tb2 = (t + di[1] - dq2[1]) & 127;
        vb2[it] = v4[base + ((size_t)pq2[1] * L_ + tb2) * 64];
        lp0[it] = (t + di[0]) & 127;
        lp1[it] = (t + di[1]) & 127;
    }
    // ---- batch 2: all weight/bias reads (16 independent b128 loads, L2-hot)
    f32x4 bb0[2], w0a[2], w1a[2], w2a[2], bb1[2], w0b[2], w1b[2], w2b[2];
    #pragma unroll
    for (int it = 0; it < 2; ++it) {
        int wo0 = lp0[it] * 8 + e4, wo1 = lp1[it] * 8 + e4;
        bb0[it] = b4[wo0]; w0a[it] = w4[wo0]; w1a[it] = w4[1024 + wo0]; w2a[it] = w4[2048 + wo0];
        bb1[it] = b4[wo1]; w0b[it] = w4[wo1]; w1b[it] = w4[1024 + wo1]; w2b[it] = w4[2048 + wo1];
    }
    // ---- compute + store
    #pragma unroll
    for (int it = 0; it < 2; ++it) {
        int t = half * 64 + tq + 32 * it;
        f32x4 acc = bb0[it] + bb1[it];
        acc += w2a[it] * (si[0] * vs[it]);
        acc += w1a[it] * (s1[0] * va1[it]);
        acc += w0a[it] * (s2[0] * va2[it]);
        acc += w2b[it] * (si[1] * vs[it]);
        acc += w1b[it] * (s1[1] * vb1[it]);
        acc += w0b[it] * (s2[1] * vb2[it]);
        o4[base + ((size_t)n * L_ + t) * 64] = acc * 0.5f;
    }
}

extern "C" void kernel_launch(void* const* d_in, const int* in_sizes, int n_in,
                              void* d_out, int out_size, void* d_ws, size_t ws_size,
                              hipStream_t stream) {
    const float* queries = (const float*)d_in[0];
    const float* keys    = (const float*)d_in[1];
    const float* values  = (const float*)d_in[2];
    const float* w_cf = (const float*)d_in[4];
    const float* b_cf = (const float*)d_in[5];
    float* out = (float*)d_out;

    float* ws    = (float*)d_ws;
    float* qm    = ws;                    // 131072 f
    float* wT    = qm + 131072;           // 12288 f
    float* bT    = wT + 12288;            // 4096 f
    float* sigp  = bT + 4096;             // 4096 f
    int*   didxp = (int*)(sigp + 4096);   // 4096 i
    int*   predp = didxp + 4096;          // 8192 i
    int*   flags = predp + 8192;          // 2048 i

    // 8 MB of corr partials live in d_out (fully overwritten by k_out)
    float* part = (float*)d_out;

    k_qmean <<<512,  256, 0, stream>>>(queries, qm);
    k_prepwb<<<16,   256, 0, stream>>>(w_cf, b_cf, wT, bT);
    k_corr  <<<256,  512, 0, stream>>>(keys, qm, part);
    k_topk  <<<2048, 64,  0, stream>>>(part, didxp, sigp, flags);
    k_fixup <<<2048, 512, 0, stream>>>(keys, qm, flags, didxp, sigp);
    k_sort  <<<32,   128, 0, stream>>>(didxp, predp);
    k_out   <<<4096, 256, 0, stream>>>(values, wT, bT, didxp, sigp, predp, out);
}

// Round 7
// 78.628 us; speedup vs baseline: 2.1685x; 1.1440x over previous
//
#include <hip/hip_runtime.h>
#include <math.h>

#define B_ 4
#define N_ 64
#define L_ 128
#define H_ 8
#define E_ 32
#define SC_ 8

typedef __attribute__((ext_vector_type(8))) short short8;
typedef __attribute__((ext_vector_type(4))) float f32x4;

__device__ __forceinline__ unsigned short f2bf(float x) {
    union { float f; unsigned u; } c; c.f = x;
    unsigned r = (c.u + 0x7fffu + ((c.u >> 16) & 1u)) >> 16;
    return (unsigned short)r;
}
__device__ __forceinline__ float bf2f(unsigned short h) {
    union { unsigned u; float f; } c; c.u = ((unsigned)h) << 16;
    return c.f;
}

// qm[b][h][e][t] = mean over n of queries[b,n,t,h,e]   (fp64 accumulate)
__global__ __launch_bounds__(256) void k_qmean(const float* __restrict__ q,
                                               float* __restrict__ qm) {
    int blk = blockIdx.x;               // b*128 + t
    int b = blk >> 7, t = blk & 127;
    int c = threadIdx.x;                // h*32 + e
    const float* p = q + (((size_t)(b * N_)) * L_ + t) * 256 + c;
    double s = 0.0;
    for (int n = 0; n < N_; ++n) s += (double)p[(size_t)n * L_ * 256];
    qm[((size_t)b * 256 + c) * L_ + t] = (float)(s * (1.0 / 64.0));
}

// wT[dt][lp*32+e] = w_cf[(e*128+lp)*3 + dt],  bT[lp*32+e] = b_cf[e*128+lp]
__global__ void k_prepwb(const float* __restrict__ w, const float* __restrict__ bias,
                         float* __restrict__ wT, float* __restrict__ bT) {
    int k = blockIdx.x * 256 + threadIdx.x;  // 4096 = lp*32+e
    int e = k & 31, lp = k >> 5;
    int c = e * L_ + lp;
    wT[k]          = w[c * 3 + 0];
    wT[4096 + k]   = w[c * 3 + 1];
    wT[8192 + k]   = w[c * 3 + 2];
    bT[k]          = bias[c];
}

// MFMA corr: part[sc][b][n][h][tau] = sum_{s in chunk, e} keys[b,n,s,h,e]*qm[b,h,e,(s+tau)%128]
// split-bf16 (hi+lo, 3 MFMAs: hh + hl + lh), mfma_f32_16x16x32_bf16, K=32 = one s-plane.
__global__ __launch_bounds__(512) void k_corr(const float* __restrict__ keys,
                                              const float* __restrict__ qm,
                                              float* __restrict__ part) {
    int blk = blockIdx.x;
    int sc = blk & 7; int bh = blk >> 3; int h = bh & 7; int b = bh >> 3;
    __shared__ unsigned short Ahi[4][64][40];
    __shared__ unsigned short Alo[4][64][40];
    __shared__ unsigned short Qhi[128][40];
    __shared__ unsigned short Qlo[128][40];
    int tid = threadIdx.x;
    int lane = tid & 63, w = tid >> 6;
    int mg = w & 1, ng = w >> 1;

    {
        int e = tid >> 4; int tq = (tid & 15) * 4;
        const float* qp = qm + ((size_t)b * 256 + h * 32 + e) * 128;
        #pragma unroll
        for (int hf = 0; hf < 2; ++hf) {
            int t0 = tq + hf * 64;
            float4 v = *(const float4*)(qp + t0);
            float vv[4] = {v.x, v.y, v.z, v.w};
            #pragma unroll
            for (int j = 0; j < 4; ++j) {
                unsigned short hi = f2bf(vv[j]);
                Qhi[t0 + j][e] = hi;
                Qlo[t0 + j][e] = f2bf(vv[j] - bf2f(hi));
            }
        }
    }
    int sn = tid >> 3; int se = (tid & 7) * 4;
    const float* kbase = keys + ((size_t)(b * N_ + sn) * L_) * 256 + h * 32 + se;
    #pragma unroll
    for (int p = 0; p < 2; ++p) {
        float4 v = *(const float4*)(kbase + (size_t)(sc * 16 + p) * 256);
        float vv[4] = {v.x, v.y, v.z, v.w};
        ushort4 h4, l4;
        unsigned short* hp = (unsigned short*)&h4;
        unsigned short* lp = (unsigned short*)&l4;
        #pragma unroll
        for (int j = 0; j < 4; ++j) {
            hp[j] = f2bf(vv[j]);
            lp[j] = f2bf(vv[j] - bf2f(hp[j]));
        }
        *(ushort4*)&Ahi[p][sn][se] = h4;
        *(ushort4*)&Alo[p][sn][se] = l4;
    }
    __syncthreads();

    f32x4 acc[2][2];
    #pragma unroll
    for (int i = 0; i < 2; ++i)
        #pragma unroll
        for (int j = 0; j < 2; ++j)
            acc[i][j] = (f32x4){0.f, 0.f, 0.f, 0.f};

    int eb = (lane >> 4) * 8;
    int rA0 = (mg * 2) * 16 + (lane & 15);
    int rA1 = rA0 + 16;
    int tau0 = (ng * 2) * 16 + (lane & 15);
    int tau1 = tau0 + 16;

    for (int it = 0; it < 8; ++it) {
        float4 stg0, stg1;
        if (it < 7) {
            stg0 = *(const float4*)(kbase + (size_t)(sc * 16 + 2 * it + 2) * 256);
            stg1 = *(const float4*)(kbase + (size_t)(sc * 16 + 2 * it + 3) * 256);
        }
        #pragma unroll
        for (int sp = 0; sp < 2; ++sp) {
            int p = 2 * it + sp;
            int slot = p & 3;
            int s = sc * 16 + p;
            short8 ah0 = *(const short8*)&Ahi[slot][rA0][eb];
            short8 ah1 = *(const short8*)&Ahi[slot][rA1][eb];
            short8 al0 = *(const short8*)&Alo[slot][rA0][eb];
            short8 al1 = *(const short8*)&Alo[slot][rA1][eb];
            int t0 = (s + tau0) & 127;
            int t1 = (s + tau1) & 127;
            short8 bh0 = *(const short8*)&Qhi[t0][eb];
            short8 bh1 = *(const short8*)&Qhi[t1][eb];
            short8 bl0 = *(const short8*)&Qlo[t0][eb];
            short8 bl1 = *(const short8*)&Qlo[t1][eb];
            acc[0][0] = __builtin_amdgcn_mfma_f32_16x16x32_bf16(ah0, bh0, acc[0][0], 0, 0, 0);
            acc[0][1] = __builtin_amdgcn_mfma_f32_16x16x32_bf16(ah0, bh1, acc[0][1], 0, 0, 0);
            acc[1][0] = __builtin_amdgcn_mfma_f32_16x16x32_bf16(ah1, bh0, acc[1][0], 0, 0, 0);
            acc[1][1] = __builtin_amdgcn_mfma_f32_16x16x32_bf16(ah1, bh1, acc[1][1], 0, 0, 0);
            acc[0][0] = __builtin_amdgcn_mfma_f32_16x16x32_bf16(ah0, bl0, acc[0][0], 0, 0, 0);
            acc[0][1] = __builtin_amdgcn_mfma_f32_16x16x32_bf16(ah0, bl1, acc[0][1], 0, 0, 0);
            acc[1][0] = __builtin_amdgcn_mfma_f32_16x16x32_bf16(ah1, bl0, acc[1][0], 0, 0, 0);
            acc[1][1] = __builtin_amdgcn_mfma_f32_16x16x32_bf16(ah1, bl1, acc[1][1], 0, 0, 0);
            acc[0][0] = __builtin_amdgcn_mfma_f32_16x16x32_bf16(al0, bh0, acc[0][0], 0, 0, 0);
            acc[0][1] = __builtin_amdgcn_mfma_f32_16x16x32_bf16(al0, bh1, acc[0][1], 0, 0, 0);
            acc[1][0] = __builtin_amdgcn_mfma_f32_16x16x32_bf16(al1, bh0, acc[1][0], 0, 0, 0);
            acc[1][1] = __builtin_amdgcn_mfma_f32_16x16x32_bf16(al1, bh1, acc[1][1], 0, 0, 0);
        }
        if (it < 7) {
            #pragma unroll
            for (int sp = 0; sp < 2; ++sp) {
                int p = 2 * it + 2 + sp;
                int slot = p & 3;
                float4 v = sp ? stg1 : stg0;
                float vv[4] = {v.x, v.y, v.z, v.w};
                ushort4 h4, l4;
                unsigned short* hp = (unsigned short*)&h4;
                unsigned short* lp = (unsigned short*)&l4;
                #pragma unroll
                for (int j = 0; j < 4; ++j) {
                    hp[j] = f2bf(vv[j]);
                    lp[j] = f2bf(vv[j] - bf2f(hp[j]));
                }
                *(ushort4*)&Ahi[slot][sn][se] = h4;
                *(ushort4*)&Alo[slot][sn][se] = l4;
            }
        }
        __syncthreads();
    }

    #pragma unroll
    for (int i = 0; i < 2; ++i) {
        int mt = mg * 2 + i;
        #pragma unroll
        for (int j = 0; j < 2; ++j) {
            int nt = ng * 2 + j;
            int tau = nt * 16 + (lane & 15);
            #pragma unroll
            for (int r = 0; r < 4; ++r) {
                int n = mt * 16 + (lane >> 4) * 4 + r;
                part[((((size_t)sc * B_ + b) * N_ + n) * H_ + h) * L_ + tau] = acc[i][j][r];
            }
        }
    }
}

// top-2 over tau per (b,n,h) + near-tie flag (v2 - v3 < margin)
__global__ __launch_bounds__(64) void k_topk(const float* __restrict__ part,
                                             int* __restrict__ didx,
                                             float* __restrict__ sig,
                                             int* __restrict__ flags) {
    int blk = blockIdx.x;               // (b*64+n)*8+h
    int lane = threadIdx.x;
    size_t rb = (size_t)blk * L_;
    const size_t stride = (size_t)B_ * N_ * H_ * L_;
    double s0 = 0.0, s1 = 0.0;
    for (int sc = 0; sc < SC_; ++sc) {
        s0 += (double)part[sc * stride + rb + lane];
        s1 += (double)part[sc * stride + rb + lane + 64];
    }
    float v0 = (float)(s0 * (1.0 / 32.0));
    float v1 = (float)(s1 * (1.0 / 32.0));

    float bv = v0; int bi = lane;
    if (v1 > v0) { bv = v1; bi = lane + 64; }
    #pragma unroll
    for (int m = 32; m; m >>= 1) {
        float ov = __shfl_xor(bv, m, 64);
        int   oi = __shfl_xor(bi, m, 64);
        if (ov > bv || (ov == bv && oi < bi)) { bv = ov; bi = oi; }
    }
    int i1 = bi; float w1v = bv;

    float c0 = (lane == i1) ? -INFINITY : v0;
    float c1 = (lane + 64 == i1) ? -INFINITY : v1;
    float bv2 = c0; int bi2 = lane;
    if (c1 > c0) { bv2 = c1; bi2 = lane + 64; }
    #pragma unroll
    for (int m = 32; m; m >>= 1) {
        float ov = __shfl_xor(bv2, m, 64);
        int   oi = __shfl_xor(bi2, m, 64);
        if (ov > bv2 || (ov == bv2 && oi < bi2)) { bv2 = ov; bi2 = oi; }
    }
    int i2 = bi2; float w2v = bv2;

    float d0 = (lane == i1 || lane == i2) ? -INFINITY : v0;
    float d1 = (lane + 64 == i1 || lane + 64 == i2) ? -INFINITY : v1;
    float bv3 = fmaxf(d0, d1);
    #pragma unroll
    for (int m = 32; m; m >>= 1) bv3 = fmaxf(bv3, __shfl_xor(bv3, m, 64));

    if (lane == 0) {
        didx[blk * 2 + 0] = i1;
        didx[blk * 2 + 1] = i2;
        sig[blk * 2 + 0] = 1.f / (1.f + expf(-w1v));
        sig[blk * 2 + 1] = 1.f / (1.f + expf(-w2v));
        flags[blk] = (w2v - bv3 < 1e-3f) ? 1 : 0;
    }
}

// exact fp64 recompute of flagged rows (jax tie semantics).
// 1024 thr = 128 tau x (2 s-halves x 4 e-octets); loads hoisted in batches of 4
// iters (16 independent b128 LDS reads) to break per-operand latency serialization.
__global__ __launch_bounds__(1024) void k_fixup(const float* __restrict__ keys,
                                                const float* __restrict__ qm,
                                                const int* __restrict__ flags,
                                                int* __restrict__ didx,
                                                float* __restrict__ sig) {
    int row = blockIdx.x;               // (b*64+n)*8+h
    if (!flags[row]) return;
    int h = row & 7; int r = row >> 3; int n = r & 63; int b = r >> 6;
    __shared__ float ks_t[L_][E_];      // [s][e] plain (reads broadcast)
    __shared__ float qs_t[L_][E_];      // [t][e] swizzled by t&7
    __shared__ double vv[8][L_];
    int tid = threadIdx.x;
    // ---- staging, fully vectorized float4
    {
        int s = tid >> 3, e4 = tid & 7;     // keys: 1024 float4 slots
        *(float4*)&ks_t[s][e4 * 4] =
            *(const float4*)&keys[(((size_t)(b * N_ + n)) * L_ + s) * 256 + h * E_ + e4 * 4];
        int e = tid >> 5, t4 = (tid & 31) * 4;  // qm: read along t, scatter-transpose
        float4 v = *(const float4*)&qm[((size_t)b * 256 + h * E_ + e) * L_ + t4];
        float vvj[4] = {v.x, v.y, v.z, v.w};
        #pragma unroll
        for (int j = 0; j < 4; ++j) {
            int t = t4 + j;
            int col = ((((e >> 2) ^ (t & 7)) << 2) | (e & 3));
            qs_t[t][col] = vvj[j];
        }
    }
    __syncthreads();
    int tau = tid & 127, g = tid >> 7;  // g: bit2 = s-half, bits1:0 = e-octet
    int sh = g >> 2, eo = g & 3;
    double a0 = 0, a1 = 0, a2 = 0, a3 = 0, a4 = 0, a5 = 0, a6 = 0, a7 = 0;
    for (int s0 = sh * 64; s0 < sh * 64 + 64; s0 += 4) {
        float4 kk[4][2], qq[4][2];
        #pragma unroll
        for (int u = 0; u < 4; ++u) {
            int s = s0 + u;
            int t = (s + tau) & 127;
            kk[u][0] = *(const float4*)&ks_t[s][eo * 8];
            kk[u][1] = *(const float4*)&ks_t[s][eo * 8 + 4];
            qq[u][0] = *(const float4*)&qs_t[t][((2 * eo) ^ (t & 7)) << 2];
            qq[u][1] = *(const float4*)&qs_t[t][((2 * eo + 1) ^ (t & 7)) << 2];
        }
        #pragma unroll
        for (int u = 0; u < 4; ++u) {
            a0 = fma((double)kk[u][0].x, (double)qq[u][0].x, a0);
            a1 = fma((double)kk[u][0].y, (double)qq[u][0].y, a1);
            a2 = fma((double)kk[u][0].z, (double)qq[u][0].z, a2);
            a3 = fma((double)kk[u][0].w, (double)qq[u][0].w, a3);
            a4 = fma((double)kk[u][1].x, (double)qq[u][1].x, a4);
            a5 = fma((double)kk[u][1].y, (double)qq[u][1].y, a5);
            a6 = fma((double)kk[u][1].z, (double)qq[u][1].z, a6);
            a7 = fma((double)kk[u][1].w, (double)qq[u][1].w, a7);
        }
    }
    vv[g][tau] = ((a0 + a1) + (a2 + a3)) + ((a4 + a5) + (a6 + a7));
    __syncthreads();
    if (tid < 64) {
        int lane = tid;
        double t0 = 0, t1 = 0;
        #pragma unroll
        for (int g2 = 0; g2 < 8; ++g2) { t0 += vv[g2][lane]; t1 += vv[g2][lane + 64]; }
        float v0 = (float)(t0 * (1.0 / 32.0));
        float v1 = (float)(t1 * (1.0 / 32.0));

        float bv = v0; int bi = lane;
        if (v1 > v0) { bv = v1; bi = lane + 64; }
        #pragma unroll
        for (int m = 32; m; m >>= 1) {
            float ov = __shfl_xor(bv, m, 64);
            int   oi = __shfl_xor(bi, m, 64);
            if (ov > bv || (ov == bv && oi < bi)) { bv = ov; bi = oi; }
        }
        int i1 = bi; float w1v = bv;

        float c0 = (lane == i1) ? -INFINITY : v0;
        float c1 = (lane + 64 == i1) ? -INFINITY : v1;
        float bv2 = c0; int bi2 = lane;
        if (c1 > c0) { bv2 = c1; bi2 = lane + 64; }
        #pragma unroll
        for (int m = 32; m; m >>= 1) {
            float ov = __shfl_xor(bv2, m, 64);
            int   oi = __shfl_xor(bi2, m, 64);
            if (ov > bv2 || (ov == bv2 && oi < bi2)) { bv2 = ov; bi2 = oi; }
        }
        if (lane == 0) {
            didx[row * 2 + 0] = i1;
            didx[row * 2 + 1] = bi2;
            sig[row * 2 + 0] = 1.f / (1.f + expf(-w1v));
            sig[row * 2 + 1] = 1.f / (1.f + expf(-bv2));
        }
    }
}

// stable argsort by (delay asc, n asc) over N=64; emit sorted-order predecessors
__global__ __launch_bounds__(128) void k_sort(const int* __restrict__ didx,
                                              int* __restrict__ pred) {
    int bh = blockIdx.x;                // b*8+h
    int b = bh >> 3, h = bh & 7;
    int tid = threadIdx.x; int i = tid >> 6; int n = tid & 63;
    __shared__ int ds[2][64];
    __shared__ int pm[2][64];
    int d = 128 - didx[((b * 64 + n) * 8 + h) * 2 + i];
    ds[i][n] = d;
    __syncthreads();
    int rank = 0;
    for (int m = 0; m < 64; ++m) {
        int dm = ds[i][m];
        rank += (dm < d || (dm == d && m < n)) ? 1 : 0;
    }
    pm[i][rank] = n;
    __syncthreads();
    int p1v = (rank >= 1) ? pm[i][rank - 1] : -1;
    int p2v = (rank >= 2) ? pm[i][rank - 2] : -1;
    int o = ((bh * 2 + i) * 64 + n) * 2;
    pred[o] = p1v; pred[o + 1] = p2v;
}

// final gather v3: branch-free, all value-gathers + weight reads preloaded into
// registers (one counted-vmcnt batch), no LDS. grid 4096 = blk*2+half, 256 thr.
__global__ __launch_bounds__(256, 2) void k_out(const float* __restrict__ values,
                                                const float* __restrict__ wT,
                                                const float* __restrict__ bT,
                                                const int* __restrict__ didx,
                                                const float* __restrict__ sig,
                                                const int* __restrict__ pred,
                                                float* __restrict__ out) {
    int bid = blockIdx.x;
    int half = bid & 1; int blk = bid >> 1;   // (b*64+n)*8+h
    int h = blk & 7; int r = blk >> 3; int n = r & 63; int b = r >> 6;
    int tid = threadIdx.x; int e4 = tid & 7; int tq = tid >> 3;  // tq 0..31

    int di[2]; float si[2];
    int pq1[2], pq2[2], dq1[2], dq2[2]; float s1[2], s2[2];
    #pragma unroll
    for (int i = 0; i < 2; ++i) {
        di[i] = didx[blk * 2 + i];
        si[i] = sig[blk * 2 + i];
        int po = (((b * 8 + h) * 2 + i) * 64 + n) * 2;
        int p1 = pred[po], p2 = pred[po + 1];
        if (p1 >= 0) { int q = ((b * 64 + p1) * 8 + h) * 2 + i; pq1[i] = p1; dq1[i] = didx[q]; s1[i] = sig[q]; }
        else         { pq1[i] = n; dq1[i] = di[i]; s1[i] = 0.f; }
        if (p2 >= 0) { int q = ((b * 64 + p2) * 8 + h) * 2 + i; pq2[i] = p2; dq2[i] = didx[q]; s2[i] = sig[q]; }
        else         { pq2[i] = n; dq2[i] = di[i]; s2[i] = 0.f; }
    }
    const f32x4* v4 = (const f32x4*)values;
    const f32x4* w4 = (const f32x4*)wT;
    const f32x4* b4 = (const f32x4*)bT;
    f32x4* o4 = (f32x4*)out;
    const size_t base = ((size_t)b * N_) * L_ * 64 + h * 8 + e4;

    // ---- batch 1: all value gathers (branch-free, 10 independent b128 loads)
    f32x4 vs[2], va1[2], va2[2], vb1[2], vb2[2];
    int lp0[2], lp1[2];
    #pragma unroll
    for (int it = 0; it < 2; ++it) {
        int t = half * 64 + tq + 32 * it;
        vs[it] = v4[base + ((size_t)n * L_ + t) * 64];
        int ta1 = (t + di[0] - dq1[0]) & 127;
        va1[it] = v4[base + ((size_t)pq1[0] * L_ + ta1) * 64];
        int ta2 = (t + di[0] - dq2[0]) & 127;
        va2[it] = v4[base + ((size_t)pq2[0] * L_ + ta2) * 64];
        int tb1 = (t + di[1] - dq1[1]) & 127;
        vb1[it] = v4[base + ((size_t)pq1[1] * L_ + tb1) * 64];
        int tb2 = (t + di[1] - dq2[1]) & 127;
        vb2[it] = v4[base + ((size_t)pq2[1] * L_ + tb2) * 64];
        lp0[it] = (t + di[0]) & 127;
        lp1[it] = (t + di[1]) & 127;
    }
    // ---- batch 2: all weight/bias reads (16 independent b128 loads, L2-hot)
    f32x4 bb0[2], w0a[2], w1a[2], w2a[2], bb1[2], w0b[2], w1b[2], w2b[2];
    #pragma unroll
    for (int it = 0; it < 2; ++it) {
        int wo0 = lp0[it] * 8 + e4, wo1 = lp1[it] * 8 + e4;
        bb0[it] = b4[wo0]; w0a[it] = w4[wo0]; w1a[it] = w4[1024 + wo0]; w2a[it] = w4[2048 + wo0];
        bb1[it] = b4[wo1]; w0b[it] = w4[wo1]; w1b[it] = w4[1024 + wo1]; w2b[it] = w4[2048 + wo1];
    }
    // ---- compute + store
    #pragma unroll
    for (int it = 0; it < 2; ++it) {
        int t = half * 64 + tq + 32 * it;
        f32x4 acc = bb0[it] + bb1[it];
        acc += w2a[it] * (si[0] * vs[it]);
        acc += w1a[it] * (s1[0] * va1[it]);
        acc += w0a[it] * (s2[0] * va2[it]);
        acc += w2b[it] * (si[1] * vs[it]);
        acc += w1b[it] * (s1[1] * vb1[it]);
        acc += w0b[it] * (s2[1] * vb2[it]);
        o4[base + ((size_t)n * L_ + t) * 64] = acc * 0.5f;
    }
}

extern "C" void kernel_launch(void* const* d_in, const int* in_sizes, int n_in,
                              void* d_out, int out_size, void* d_ws, size_t ws_size,
                              hipStream_t stream) {
    const float* queries = (const float*)d_in[0];
    const float* keys    = (const float*)d_in[1];
    const float* values  = (const float*)d_in[2];
    const float* w_cf = (const float*)d_in[4];
    const float* b_cf = (const float*)d_in[5];
    float* out = (float*)d_out;

    float* ws    = (float*)d_ws;
    float* qm    = ws;                    // 131072 f
    float* wT    = qm + 131072;           // 12288 f
    float* bT    = wT + 12288;            // 4096 f
    float* sigp  = bT + 4096;             // 4096 f
    int*   didxp = (int*)(sigp + 4096);   // 4096 i
    int*   predp = didxp + 4096;          // 8192 i
    int*   flags = predp + 8192;          // 2048 i

    // 8 MB of corr partials live in d_out (fully overwritten by k_out)
    float* part = (float*)d_out;

    k_qmean <<<512,  256, 0, stream>>>(queries, qm);
    k_prepwb<<<16,   256, 0, stream>>>(w_cf, b_cf, wT, bT);
    k_corr  <<<256,  512, 0, stream>>>(keys, qm, part);
    k_topk  <<<2048, 64,  0, stream>>>(part, didxp, sigp, flags);
    k_fixup <<<2048, 1024, 0, stream>>>(keys, qm, flags, didxp, sigp);
    k_sort  <<<32,   128, 0, stream>>>(didxp, predp);
    k_out   <<<4096, 256, 0, stream>>>(values, wT, bT, didxp, sigp, predp, out);
}